// Round 3
// baseline (648.453 us; speedup 1.0000x reference)
//
#include <hip/hip_runtime.h>
#include <math.h>

#define D 1024
#define V 16384
#define NROWS 8192
#define NCAND 128
#define DELTA 0.03f

typedef __bf16 bf16_t;
typedef bf16_t bf16x8 __attribute__((ext_vector_type(8)));
typedef float f32x4 __attribute__((ext_vector_type(4)));

__device__ __forceinline__ unsigned int sortable_key(float v) {
    unsigned int b = __float_as_uint(v);
    return (b & 0x80000000u) ? ~b : (b | 0x80000000u);
}
__device__ __forceinline__ float unkey(unsigned int key) {
    unsigned int b = (key & 0x80000000u) ? (key & 0x7FFFFFFFu) : ~key;
    return __uint_as_float(b);
}
__device__ __forceinline__ uint2 trunc4(float4 v) {
    unsigned int u0 = __float_as_uint(v.x), u1 = __float_as_uint(v.y);
    unsigned int u2 = __float_as_uint(v.z), u3 = __float_as_uint(v.w);
    uint2 hw;
    hw.x = (u0 >> 16) | (u1 & 0xFFFF0000u);
    hw.y = (u2 >> 16) | (u3 & 0xFFFF0000u);
    return hw;
}
__device__ __forceinline__ void split4(float4 v, uint2& hw, uint2& lw) {
    unsigned int u0 = __float_as_uint(v.x), u1 = __float_as_uint(v.y);
    unsigned int u2 = __float_as_uint(v.z), u3 = __float_as_uint(v.w);
    float l0 = v.x - __uint_as_float(u0 & 0xFFFF0000u);
    float l1 = v.y - __uint_as_float(u1 & 0xFFFF0000u);
    float l2 = v.z - __uint_as_float(u2 & 0xFFFF0000u);
    float l3 = v.w - __uint_as_float(u3 & 0xFFFF0000u);
    hw.x = (u0 >> 16) | (u1 & 0xFFFF0000u);
    hw.y = (u2 >> 16) | (u3 & 0xFFFF0000u);
    lw.x = (__float_as_uint(l0) >> 16) | (__float_as_uint(l1) & 0xFFFF0000u);
    lw.y = (__float_as_uint(l2) >> 16) | (__float_as_uint(l3) & 0xFFFF0000u);
}

// async 16B global->LDS copy (per-lane global addr, wave-uniform LDS base + lane*16)
__device__ __forceinline__ void gload16(const ushort* g, ushort* s) {
    __builtin_amdgcn_global_load_lds((const __attribute__((address_space(1))) void*)g,
                                     (__attribute__((address_space(3))) void*)s,
                                     16, 0, 0);
}

// ---------------- merged: row L2-norms of W and X + zero of packed/count ----------------
__global__ __launch_bounds__(256) void prep_kernel(const float* __restrict__ W,
                                                   const float* __restrict__ X,
                                                   float* __restrict__ RK,
                                                   float* __restrict__ RQ,
                                                   unsigned long long* __restrict__ packed,
                                                   unsigned int* __restrict__ count) {
    int tid = threadIdx.x;
    int row = blockIdx.x * 4 + (tid >> 6);
    int lane = tid & 63;
    const float* src;
    float* dst;
    if (row < V) { src = W + (size_t)row * D; dst = RK + row; }
    else { src = X + (size_t)(row - V) * D; dst = RQ + (row - V); }
    const float4* p = (const float4*)src;
    float ss = 0.f;
#pragma unroll
    for (int i = 0; i < 4; ++i) {
        float4 v = p[lane + 64 * i];
        ss += v.x * v.x + v.y * v.y + v.z * v.z + v.w * v.w;
    }
#pragma unroll
    for (int m = 32; m >= 1; m >>= 1) ss += __shfl_xor(ss, m, 64);
    if (lane == 0) {
        *dst = rsqrtf(fmaxf(ss, 1e-12f));
        if (row >= V) { packed[row - V] = 0ull; count[row - V] = 0u; }
    }
}

// ---------------- truncate rows of src into MFMA-fragment-packed bf16 ----------------
// dst[((t16*32 + kc)*64 + lane)*8 + j]: t16=row>>4, lane=(row&15)|((kk>>3)<<4), j=kk&7 (kk=k&31)
__global__ __launch_bounds__(256) void pack_kernel(const float* __restrict__ src,
                                                   ushort* __restrict__ dst) {
    int f = blockIdx.x * 256 + threadIdx.x;
    int row = f >> 8;
    int kq = f & 255;
    int k0 = kq * 4;
    float4 v = *((const float4*)(src + (size_t)row * D) + kq);
    uint2 hw = trunc4(v);
    int t16 = row >> 4, m = row & 15;
    int kc = k0 >> 5, kk = k0 & 31;
    int lane = m | ((kk >> 3) << 4);
    int j0 = kk & 4;
    int idx = ((t16 * 32 + kc) * 64 + lane) * 8 + j0;
    *(uint2*)(dst + idx) = hw;
}

// ---------------- approx sim GEMM: 256x256 tile, BK=64, 4-phase-per-K-tile pipeline ----------------
// m201-style schedule in plain HIP. 8 waves (2M x 4N), per-wave 128x64 out.
// Phase = C-quadrant (mt-half H x kc Y) = 16 MFMA. Per phase:
//   {vmcnt(N) counted; issue 1-3 stage calls for kt+1; ds_read 4-8 frags} BAR {lgkm(0); setprio;
//    16 MFMA; setprio} BAR
// Staggered staging (per wave, per K-tile, 8 gload16 calls g1..g8); derived steady-state waits:
//   preP0: vmcnt(4), preP1: vmcnt(4), preP2: vmcnt(5), preP3: vmcnt(4) — never 0 in-loop;
//   each waited load was issued 3-4 phases (~1000+ cyc) earlier.
// LDS: 2 x 64KB dbuf (A 32KB + B 32KB), unit = 1KB frag (64 lanes x 16B) -> linear
// global_load_lds dests and conflict-free lane-linear ds_read_b128 (no swizzle needed).
__global__ __launch_bounds__(512, 2) void gemm1_kernel(const ushort* __restrict__ Xhi,
                                                       const ushort* __restrict__ Wfrag,
                                                       const float* __restrict__ RK,
                                                       unsigned long long* __restrict__ packed,
                                                       unsigned int* __restrict__ count,
                                                       ushort* __restrict__ candCol,
                                                       int colBase, int perX) {
    __shared__ __align__(16) unsigned char ldsraw[131072];
    ushort* lds = (ushort*)ldsraw;

    const int tid = threadIdx.x;
    const int l = tid & 63;
    const int w = tid >> 6;                 // 0..7
    const int wy = w >> 2, wx = w & 3;      // per-wave: rows wy*128.., cols wx*64..

    const int lin = blockIdx.x;
    const int x = lin & 7;                  // XCD
    const int j = lin >> 3;
    const int rt = j / perX;
    const int ctl = x * perX + (j - rt * perX);
    const int rowBase = rt * 256;
    const int cwLocal = ctl * 256;

    f32x4 acc[8][4];
#pragma unroll
    for (int mt = 0; mt < 8; ++mt)
#pragma unroll
        for (int nt = 0; nt < 4; ++nt) acc[mt][nt] = (f32x4)0.f;

    // A frag-unit rfrag staged by wave w for half H: {0..3,8..11} (H=0) / {4..7,12..15} (H=1)
    const int arf0 = (w & 3) + ((w >> 2) << 3);   // + H*4
    // stage one A frag-unit (8KB block-wide): LDS unit Y*16+rfrag, src frag (rt*16+rfrag, kt*2+Y)
    auto stageA = [&](int sb, int kts, int H, int Y) {
        int rfrag = arf0 + H * 4;
        gload16(Xhi + ((size_t)((rt * 16 + rfrag) * 32 + (kts * 2 + Y)) * 64) * 8 + l * 8,
                lds + sb + (Y * 16 + rfrag) * 512);
    };
    // stage one B frag-unit: cfrag = half*8 + w
    auto stageB = [&](int sb, int kts, int Y, int half) {
        int cfrag = half * 8 + w;
        gload16(Wfrag + ((size_t)((ctl * 16 + cfrag) * 32 + (kts * 2 + Y)) * 64) * 8 + l * 8,
                lds + sb + 16384 + (Y * 16 + cfrag) * 512);
    };

    // prologue: stage K-tile 0 into buf0 (order g1..g8), wait first 4, barrier
    stageA(0, 0, 0, 0);   // g1  A h0 k0
    stageB(0, 0, 0, 0);   // g2  B k0 a
    stageB(0, 0, 0, 1);   // g3  B k0 b
    stageA(0, 0, 1, 0);   // g4  A h1 k0
    stageA(0, 0, 1, 1);   // g5  A h1 k1
    stageB(0, 0, 1, 0);   // g6  B k1 a
    stageB(0, 0, 1, 1);   // g7  B k1 b
    stageA(0, 0, 0, 1);   // g8  A h0 k1
    asm volatile("s_waitcnt vmcnt(4)" ::: "memory");
    __builtin_amdgcn_sched_barrier(0);
    __builtin_amdgcn_s_barrier();

    bf16x8 av[4], bv[4];
#pragma unroll 1
    for (int kt = 0; kt < 16; ++kt) {
        const int base = (kt & 1) << 15;          // read buf (elements)
        const int sb = ((kt & 1) ^ 1) << 15;      // stage buf
        const int kts = (kt + 1) & 15;            // wrap at tail: stages dead data into free buf

        // ======== P0: (h0, k0) — read A-h0k0 + B-k0 ========
        asm volatile("s_waitcnt vmcnt(4)" ::: "memory");
        __builtin_amdgcn_sched_barrier(0);
        stageA(sb, kts, 0, 0); stageB(sb, kts, 0, 0); stageB(sb, kts, 0, 1);  // g1,g2,g3
#pragma unroll
        for (int mi = 0; mi < 4; ++mi)
            av[mi] = *(const bf16x8*)&lds[base + (wy * 8 + mi) * 512 + l * 8];
#pragma unroll
        for (int nt = 0; nt < 4; ++nt)
            bv[nt] = *(const bf16x8*)&lds[base + 16384 + (wx * 4 + nt) * 512 + l * 8];
        __builtin_amdgcn_s_barrier();
        asm volatile("s_waitcnt lgkmcnt(0)" ::: "memory");
        __builtin_amdgcn_sched_barrier(0);
        __builtin_amdgcn_s_setprio(1);
#pragma unroll
        for (int nt = 0; nt < 4; ++nt)
#pragma unroll
            for (int mi = 0; mi < 4; ++mi)
                acc[mi][nt] = __builtin_amdgcn_mfma_f32_16x16x32_bf16(av[mi], bv[nt], acc[mi][nt], 0, 0, 0);
        __builtin_amdgcn_s_setprio(0);
        __builtin_amdgcn_s_barrier();

        // ======== P1: (h1, k0) — read A-h1k0, reuse B-k0 ========
        asm volatile("s_waitcnt vmcnt(4)" ::: "memory");
        __builtin_amdgcn_sched_barrier(0);
        stageA(sb, kts, 1, 0); stageA(sb, kts, 1, 1);                          // g4,g5
#pragma unroll
        for (int mi = 0; mi < 4; ++mi)
            av[mi] = *(const bf16x8*)&lds[base + (wy * 8 + 4 + mi) * 512 + l * 8];
        __builtin_amdgcn_s_barrier();
        asm volatile("s_waitcnt lgkmcnt(0)" ::: "memory");
        __builtin_amdgcn_sched_barrier(0);
        __builtin_amdgcn_s_setprio(1);
#pragma unroll
        for (int nt = 0; nt < 4; ++nt)
#pragma unroll
            for (int mi = 0; mi < 4; ++mi)
                acc[4 + mi][nt] = __builtin_amdgcn_mfma_f32_16x16x32_bf16(av[mi], bv[nt], acc[4 + mi][nt], 0, 0, 0);
        __builtin_amdgcn_s_setprio(0);
        __builtin_amdgcn_s_barrier();

        // ======== P2: (h1, k1) — read A-h1k1 + B-k1 ========
        asm volatile("s_waitcnt vmcnt(5)" ::: "memory");
        __builtin_amdgcn_sched_barrier(0);
        stageB(sb, kts, 1, 0); stageB(sb, kts, 1, 1);                          // g6,g7
#pragma unroll
        for (int mi = 0; mi < 4; ++mi)
            av[mi] = *(const bf16x8*)&lds[base + (16 + wy * 8 + 4 + mi) * 512 + l * 8];
#pragma unroll
        for (int nt = 0; nt < 4; ++nt)
            bv[nt] = *(const bf16x8*)&lds[base + 16384 + (16 + wx * 4 + nt) * 512 + l * 8];
        __builtin_amdgcn_s_barrier();
        asm volatile("s_waitcnt lgkmcnt(0)" ::: "memory");
        __builtin_amdgcn_sched_barrier(0);
        __builtin_amdgcn_s_setprio(1);
#pragma unroll
        for (int nt = 0; nt < 4; ++nt)
#pragma unroll
            for (int mi = 0; mi < 4; ++mi)
                acc[4 + mi][nt] = __builtin_amdgcn_mfma_f32_16x16x32_bf16(av[mi], bv[nt], acc[4 + mi][nt], 0, 0, 0);
        __builtin_amdgcn_s_setprio(0);
        __builtin_amdgcn_s_barrier();

        // ======== P3: (h0, k1) — read A-h0k1, reuse B-k1 ========
        asm volatile("s_waitcnt vmcnt(4)" ::: "memory");
        __builtin_amdgcn_sched_barrier(0);
        stageA(sb, kts, 0, 1);                                                 // g8
#pragma unroll
        for (int mi = 0; mi < 4; ++mi)
            av[mi] = *(const bf16x8*)&lds[base + (16 + wy * 8 + mi) * 512 + l * 8];
        __builtin_amdgcn_s_barrier();
        asm volatile("s_waitcnt lgkmcnt(0)" ::: "memory");
        __builtin_amdgcn_sched_barrier(0);
        __builtin_amdgcn_s_setprio(1);
#pragma unroll
        for (int nt = 0; nt < 4; ++nt)
#pragma unroll
            for (int mi = 0; mi < 4; ++mi)
                acc[mi][nt] = __builtin_amdgcn_mfma_f32_16x16x32_bf16(av[mi], bv[nt], acc[mi][nt], 0, 0, 0);
        __builtin_amdgcn_s_setprio(0);
        __builtin_amdgcn_s_barrier();
    }
    // drain wrap-staged tail loads before the epilogue overlays LDS
    asm volatile("s_waitcnt vmcnt(0)" ::: "memory");
    __builtin_amdgcn_s_barrier();

    // ---- epilogue stage 1: block-level per-row max -> global running max ----
    unsigned long long (*red)[4] = (unsigned long long (*)[4])ldsraw;   // 256 x 4 x 8B = 8KB
    float* gthr = (float*)(ldsraw + 16384);                             // 1KB @ 16KB

    const int q = l >> 4, c = l & 15;
    float rk_l[4];
#pragma unroll
    for (int nt = 0; nt < 4; ++nt) rk_l[nt] = RK[colBase + cwLocal + wx * 64 + nt * 16 + c];
#pragma unroll
    for (int mt = 0; mt < 8; ++mt) {
#pragma unroll
        for (int r = 0; r < 4; ++r) {
            unsigned long long pk = 0;
#pragma unroll
            for (int nt = 0; nt < 4; ++nt) {
                float v = acc[mt][nt][r] * rk_l[nt];
                int col = colBase + cwLocal + wx * 64 + nt * 16 + c;
                unsigned long long p = ((unsigned long long)sortable_key(v) << 32) |
                                       (unsigned long long)(~(unsigned int)col);
                if (p > pk) pk = p;
            }
#pragma unroll
            for (int m = 1; m < 16; m <<= 1) {
                unsigned long long o = __shfl_xor(pk, m, 64);
                if (o > pk) pk = o;
            }
            if (c == 0) red[wy * 128 + mt * 16 + q * 4 + r][wx] = pk;
        }
    }
    __syncthreads();
    if (tid < 256) {
        unsigned long long a = red[tid][0];
#pragma unroll
        for (int i = 1; i < 4; ++i) { unsigned long long bb = red[tid][i]; if (bb > a) a = bb; }
        unsigned long long old = atomicMax(packed + (rowBase + tid), a);
        unsigned long long g = (old > a) ? old : a;
        gthr[tid] = unkey((unsigned int)(g >> 32)) - DELTA;
    }
    __syncthreads();
    // ---- epilogue stage 2: append candidates within DELTA of known running max ----
#pragma unroll
    for (int mt = 0; mt < 8; ++mt) {
#pragma unroll
        for (int r = 0; r < 4; ++r) {
            int lrow = wy * 128 + mt * 16 + q * 4 + r;
            float thr = gthr[lrow];
            int grow = rowBase + lrow;
#pragma unroll
            for (int nt = 0; nt < 4; ++nt) {
                float v = acc[mt][nt][r] * rk_l[nt];
                if (v >= thr) {
                    unsigned int slot = atomicAdd(count + grow, 1u);
                    if (slot < NCAND) {
                        int col = colBase + cwLocal + wx * 64 + nt * 16 + c;
                        candCol[(size_t)grow * NCAND + slot] = (ushort)col;
                    }
                }
            }
        }
    }
}

// ---------------- exact fp32 rescore + LN stats (merged) ----------------
__global__ __launch_bounds__(256) void rescore_kernel(const float* __restrict__ X,
                                                      const float* __restrict__ W,
                                                      const float* __restrict__ RK,
                                                      const float* __restrict__ RQ,
                                                      const unsigned int* __restrict__ count,
                                                      const ushort* __restrict__ candCol,
                                                      float* __restrict__ outIdx,
                                                      float* __restrict__ outSim,
                                                      int* __restrict__ idxArr,
                                                      float* __restrict__ MU,
                                                      float* __restrict__ RS) {
    int wave = threadIdx.x >> 6, l = threadIdx.x & 63;
    int row = blockIdx.x * 4 + wave;
    unsigned int n = count[row];
    if (n > NCAND) n = NCAND;
    const float4* X4 = (const float4*)X + (size_t)row * 256;
    unsigned long long best = 0;
    for (unsigned int i = 0; i < n; ++i) {
        int col = (int)candCol[(size_t)row * NCAND + i];
        const float4* W4 = (const float4*)W + (size_t)col * 256;
        float s = 0.f;
#pragma unroll
        for (int jj = 0; jj < 4; ++jj) {
            float4 a = X4[jj * 64 + l];
            float4 b = W4[jj * 64 + l];
            s += a.x * b.x + a.y * b.y + a.z * b.z + a.w * b.w;
        }
#pragma unroll
        for (int m = 32; m >= 1; m >>= 1) s += __shfl_xor(s, m, 64);
        float v = s * RK[col];
        unsigned long long pk = ((unsigned long long)sortable_key(v) << 32) |
                                (unsigned long long)(~(unsigned int)col);
        if (pk > best) best = pk;
    }
    int idx = (int)(~(unsigned int)(best & 0xFFFFFFFFull)) & 0xFFFF;
    const float4* Z4 = (const float4*)W + (size_t)idx * 256;
    float s = 0.f, s2 = 0.f;
#pragma unroll
    for (int jj = 0; jj < 4; ++jj) {
        float4 a = X4[jj * 64 + l];
        float4 z = Z4[jj * 64 + l];
        float4 e;
        e.x = (z.x - a.x) + a.x;
        e.y = (z.y - a.y) + a.y;
        e.z = (z.z - a.z) + a.z;
        e.w = (z.w - a.w) + a.w;
        s  += e.x + e.y + e.z + e.w;
        s2 += e.x * e.x + e.y * e.y + e.z * e.z + e.w * e.w;
    }
#pragma unroll
    for (int m = 32; m >= 1; m >>= 1) {
        s  += __shfl_xor(s, m, 64);
        s2 += __shfl_xor(s2, m, 64);
    }
    if (l == 0) {
        outIdx[row] = (float)idx;
        outSim[row] = unkey((unsigned int)(best >> 32)) * RQ[row];
        idxArr[row] = idx;
        float mean = s * (1.f / D);
        float var  = s2 * (1.f / D) - mean * mean;
        MU[row] = mean;
        RS[row] = rsqrtf(var + 1e-6f);
    }
}

// ---------------- projection GEMM: bf16 3-pass MFMA, LN fused into A staging ----------------
__global__ __launch_bounds__(256, 2) void gemm2_kernel(const float* __restrict__ X,
                                                       const float* __restrict__ W,
                                                       const int* __restrict__ idxArr,
                                                       const float* __restrict__ MU,
                                                       const float* __restrict__ RS,
                                                       const float* __restrict__ gamma,
                                                       const float* __restrict__ beta,
                                                       const float* __restrict__ B,
                                                       float* __restrict__ Out) {
    __shared__ ushort Ah[2][8][64][8];
    __shared__ ushort Al[2][8][64][8];
    __shared__ ushort Bh2[2][8][64][8];
    __shared__ ushort Bl2[2][8][64][8];
    __shared__ float Gs[1024];
    __shared__ float Bt[1024];

    const int tid = threadIdx.x;
    const int l = tid & 63;
    const int wave = tid >> 6;
    const int wy = wave >> 1, wx = wave & 1;
    const int rowBase = blockIdx.y * 128;
    const int nBase   = blockIdx.x * 128;

    *(float4*)&Gs[tid * 4] = *(const float4*)(gamma + tid * 4);
    *(float4*)&Bt[tid * 4] = *(const float4*)(beta + tid * 4);

    f32x4 acc[4][4];
#pragma unroll
    for (int mt = 0; mt < 4; ++mt)
#pragma unroll
        for (int nt = 0; nt < 4; ++nt) acc[mt][nt] = (f32x4)0.f;

    const int srow = tid >> 3, skq = tid & 7;
    const int sn = tid & 127, sdq = tid >> 7;
    int aidx[4];
    float amu[4], ars[4];
#pragma unroll
    for (int i = 0; i < 4; ++i) {
        int grow = rowBase + srow + i * 32;
        aidx[i] = idxArr[grow];
        amu[i] = MU[grow];
        ars[i] = RS[grow];
    }

    __syncthreads();

    float4 pz[4], pxv[4], pbv[4];
#pragma unroll
    for (int i = 0; i < 4; ++i) {
        int col = skq * 4;
        pz[i]  = *(const float4*)(W + (size_t)aidx[i] * D + col);
        pxv[i] = *(const float4*)(X + (size_t)(rowBase + srow + i * 32) * D + col);
    }
#pragma unroll
    for (int i = 0; i < 4; ++i) {
        const float* bp = B + (size_t)((sdq + i * 2) * 4) * D + nBase + sn;
        pbv[i] = {bp[0], bp[D], bp[2 * D], bp[3 * D]};
    }

    for (int kc = 0; kc < 32; ++kc) {
        const int bsel = kc & 1;
#pragma unroll
        for (int i = 0; i < 4; ++i) {
            int row = srow + i * 32;
            int col = kc * 32 + skq * 4;
            float4 z = pz[i], xv = pxv[i];
            float4 g  = *(const float4*)&Gs[col];
            float4 bb = *(const float4*)&Bt[col];
            float4 a;
            a.x = (((z.x - xv.x) + xv.x) - amu[i]) * ars[i] * g.x + bb.x;
            a.y = (((z.y - xv.y) + xv.y) - amu[i]) * ars[i] * g.y + bb.y;
            a.z = (((z.z - xv.z) + xv.z) - amu[i]) * ars[i] * g.z + bb.z;
            a.w = (((z.w - xv.w) + xv.w) - amu[i]) * ars[i] * g.w + bb.w;
            uint2 hw, lw;
            split4(a, hw, lw);
            int tile = row >> 4;
            int lf = (row & 15) | ((skq >> 1) << 4);
            int j0 = (skq & 1) * 4;
            *(uint2*)&Ah[bsel][tile][lf][j0] = hw;
            *(uint2*)&Al[bsel][tile][lf][j0] = lw;
        }
#pragma unroll
        for (int i = 0; i < 4; ++i) {
            int dq = sdq + i * 2;
            uint2 hw, lw;
            split4(pbv[i], hw, lw);
            int tile = sn >> 4;
            int lf = (sn & 15) | ((dq >> 1) << 4);
            int j0 = (dq & 1) * 4;
            *(uint2*)&Bh2[bsel][tile][lf][j0] = hw;
            *(uint2*)&Bl2[bsel][tile][lf][j0] = lw;
        }
        __syncthreads();
        float4 pzn[4], pxvn[4], pbvn[4];
        if (kc < 31) {
#pragma unroll
            for (int i = 0; i < 4; ++i) {
                int col = (kc + 1) * 32 + skq * 4;
                pzn[i]  = *(const float4*)(W + (size_t)aidx[i] * D + col);
                pxvn[i] = *(const float4*)(X + (size_t)(rowBase + srow + i * 32) * D + col);
            }
#pragma unroll
            for (int i = 0; i < 4; ++i) {
                const float* bp = B + (size_t)((kc + 1) * 32 + (sdq + i * 2) * 4) * D + nBase + sn;
                pbvn[i] = {bp[0], bp[D], bp[2 * D], bp[3 * D]};
            }
        }
        bf16x8 fah[4], fal[4];
#pragma unroll
        for (int mt = 0; mt < 4; ++mt) {
            fah[mt] = *(const bf16x8*)&Ah[bsel][wy * 4 + mt][l][0];
            fal[mt] = *(const bf16x8*)&Al[bsel][wy * 4 + mt][l][0];
        }
#pragma unroll
        for (int nt = 0; nt < 4; ++nt) {
            bf16x8 bh = *(const bf16x8*)&Bh2[bsel][wx * 4 + nt][l][0];
            bf16x8 bl = *(const bf16x8*)&Bl2[bsel][wx * 4 + nt][l][0];
#pragma unroll
            for (int mt = 0; mt < 4; ++mt) {
                acc[mt][nt] = __builtin_amdgcn_mfma_f32_16x16x32_bf16(fah[mt], bh, acc[mt][nt], 0, 0, 0);
                acc[mt][nt] = __builtin_amdgcn_mfma_f32_16x16x32_bf16(fah[mt], bl, acc[mt][nt], 0, 0, 0);
                acc[mt][nt] = __builtin_amdgcn_mfma_f32_16x16x32_bf16(fal[mt], bh, acc[mt][nt], 0, 0, 0);
            }
        }
        if (kc < 31) {
#pragma unroll
            for (int i = 0; i < 4; ++i) {
                pz[i] = pzn[i]; pxv[i] = pxvn[i]; pbv[i] = pbvn[i];
            }
        }
    }

    const int q = l >> 4, c = l & 15;
#pragma unroll
    for (int mt = 0; mt < 4; ++mt)
#pragma unroll
        for (int nt = 0; nt < 4; ++nt)
#pragma unroll
            for (int r = 0; r < 4; ++r) {
                int grow = rowBase + wy * 64 + mt * 16 + q * 4 + r;
                int gcol = nBase + wx * 64 + nt * 16 + c;
                Out[(size_t)grow * D + gcol] = acc[mt][nt][r];
            }
}

extern "C" void kernel_launch(void* const* d_in, const int* in_sizes, int n_in,
                              void* d_out, int out_size, void* d_ws, size_t ws_size,
                              hipStream_t stream) {
    const float* X     = (const float*)d_in[0];
    const float* W     = (const float*)d_in[1];
    const float* gamma = (const float*)d_in[2];
    const float* beta  = (const float*)d_in[3];
    const float* OW    = (const float*)d_in[4];

    float* out    = (float*)d_out;
    float* outIdx = out;
    float* outSim = out + NROWS;
    float* outO   = out + 2 * NROWS;

    // scratch carved from the 32 MB outO region (all consumed before gemm2 writes it):
    //   Xhi 16 MB | Wfrag 12 MB (per-chunk, reused) | candCol u16 2 MB | count 32 KB
    ushort* Xhi   = (ushort*)outO;
    ushort* Wfrag = Xhi + (size_t)NROWS * D;                    // 12 MB = 6144 rows max
    ushort* candCol = Wfrag + (size_t)6144 * D;
    unsigned int* count = (unsigned int*)(candCol + (size_t)NROWS * NCAND);

    // workspace — ~320 KB
    unsigned long long* packed = (unsigned long long*)d_ws;
    float* RK     = (float*)(packed + NROWS);
    float* RQ     = RK + V;
    float* MU     = RQ + NROWS;
    float* RS     = MU + NROWS;
    int*   idxArr = (int*)(RS + NROWS);

    hipLaunchKernelGGL(prep_kernel, dim3((V + NROWS) / 4), dim3(256), 0, stream,
                       W, X, RK, RQ, packed, count);
    hipLaunchKernelGGL(pack_kernel, dim3(NROWS), dim3(256), 0, stream, X, Xhi);

    // W chunks: 6144, 6144, 4096 codebook rows
    const int chunkRows[3] = {6144, 6144, 4096};
    int colBase = 0;
    for (int ch = 0; ch < 3; ++ch) {
        int rows = chunkRows[ch];
        int perX = (rows / 256) / 8;   // 256-col tiles per XCD: 3, 3, 2
        hipLaunchKernelGGL(pack_kernel, dim3(rows), dim3(256), 0, stream,
                           W + (size_t)colBase * D, Wfrag);
        hipLaunchKernelGGL(gemm1_kernel, dim3((NROWS / 256) * (rows / 256)), dim3(512), 0, stream,
                           Xhi, Wfrag, RK, packed, count, candCol, colBase, perX);
        colBase += rows;
    }

    hipLaunchKernelGGL(rescore_kernel, dim3(NROWS / 4), dim3(256), 0, stream,
                       X, W, RK, RQ, count, candCol, outIdx, outSim, idxArr, MU, RS);
    hipLaunchKernelGGL(gemm2_kernel, dim3(D / 128, NROWS / 128), dim3(256), 0, stream,
                       X, W, idxArr, MU, RS, gamma, beta, OW, outO);
}

// Round 4
// 583.930 us; speedup vs baseline: 1.1105x; 1.1105x over previous
//
#include <hip/hip_runtime.h>
#include <math.h>

#define D 1024
#define V 16384
#define NROWS 8192
#define NCAND 256
#define DELTA 0.15f

typedef __bf16 bf16_t;
typedef bf16_t bf16x8 __attribute__((ext_vector_type(8)));
typedef float f32x4 __attribute__((ext_vector_type(4)));
typedef int i32x4 __attribute__((ext_vector_type(4)));

__device__ __forceinline__ unsigned int sortable_key(float v) {
    unsigned int b = __float_as_uint(v);
    return (b & 0x80000000u) ? ~b : (b | 0x80000000u);
}
__device__ __forceinline__ float unkey(unsigned int key) {
    unsigned int b = (key & 0x80000000u) ? (key & 0x7FFFFFFFu) : ~key;
    return __uint_as_float(b);
}
__device__ __forceinline__ void split4(float4 v, uint2& hw, uint2& lw) {
    unsigned int u0 = __float_as_uint(v.x), u1 = __float_as_uint(v.y);
    unsigned int u2 = __float_as_uint(v.z), u3 = __float_as_uint(v.w);
    float l0 = v.x - __uint_as_float(u0 & 0xFFFF0000u);
    float l1 = v.y - __uint_as_float(u1 & 0xFFFF0000u);
    float l2 = v.z - __uint_as_float(u2 & 0xFFFF0000u);
    float l3 = v.w - __uint_as_float(u3 & 0xFFFF0000u);
    hw.x = (u0 >> 16) | (u1 & 0xFFFF0000u);
    hw.y = (u2 >> 16) | (u3 & 0xFFFF0000u);
    lw.x = (__float_as_uint(l0) >> 16) | (__float_as_uint(l1) & 0xFFFF0000u);
    lw.y = (__float_as_uint(l2) >> 16) | (__float_as_uint(l3) & 0xFFFF0000u);
}

// ---------------- merged: row L2-norms + row amax (for i8 scales) of W and X ----------------
__global__ __launch_bounds__(256) void prep_kernel(const float* __restrict__ W,
                                                   const float* __restrict__ X,
                                                   float* __restrict__ RK,
                                                   float* __restrict__ RQ,
                                                   float* __restrict__ SA,
                                                   float* __restrict__ SB,
                                                   float* __restrict__ RKS,
                                                   unsigned long long* __restrict__ packed,
                                                   unsigned int* __restrict__ count) {
    int tid = threadIdx.x;
    int row = blockIdx.x * 4 + (tid >> 6);
    int lane = tid & 63;
    const float* src = (row < V) ? (W + (size_t)row * D) : (X + (size_t)(row - V) * D);
    const float4* p = (const float4*)src;
    float ss = 0.f, am = 0.f;
#pragma unroll
    for (int i = 0; i < 4; ++i) {
        float4 v = p[lane + 64 * i];
        ss += v.x * v.x + v.y * v.y + v.z * v.z + v.w * v.w;
        am = fmaxf(am, fmaxf(fmaxf(fabsf(v.x), fabsf(v.y)), fmaxf(fabsf(v.z), fabsf(v.w))));
    }
#pragma unroll
    for (int m = 32; m >= 1; m >>= 1) {
        ss += __shfl_xor(ss, m, 64);
        am = fmaxf(am, __shfl_xor(am, m, 64));
    }
    if (lane == 0) {
        float rk = rsqrtf(fmaxf(ss, 1e-12f));
        float s = am * (1.f / 127.f);
        if (row < V) {
            RK[row] = rk;
            SB[row] = s;
            RKS[row] = rk * s;
        } else {
            RQ[row - V] = rk;
            SA[row - V] = s;
            packed[row - V] = 0ull;
            count[row - V] = 0u;
        }
    }
}

// ---------------- quantize rows into MFMA-fragment-packed i8 (16x16x64 layout) ----------------
// element (row, k): unit = (row>>4)*16 + (k>>6); lane = (row&15) | (((k&63)>>4)<<4); byte j = k&15
// unit is 1024 bytes = 64 lanes x 16 B (linear per-lane 16B fragments).
__global__ __launch_bounds__(256) void pack_i8_kernel(const float* __restrict__ src,
                                                      const float* __restrict__ S,
                                                      unsigned char* __restrict__ dst) {
    int tid = threadIdx.x;
    int row = blockIdx.x;
    int k0 = tid * 4;
    float4 v = *((const float4*)(src + (size_t)row * D) + tid);
    float s = S[row];
    float inv = (s > 0.f) ? (1.f / s) : 0.f;
    int q0 = (int)rintf(v.x * inv), q1 = (int)rintf(v.y * inv);
    int q2 = (int)rintf(v.z * inv), q3 = (int)rintf(v.w * inv);
    q0 = q0 > 127 ? 127 : (q0 < -127 ? -127 : q0);
    q1 = q1 > 127 ? 127 : (q1 < -127 ? -127 : q1);
    q2 = q2 > 127 ? 127 : (q2 < -127 ? -127 : q2);
    q3 = q3 > 127 ? 127 : (q3 < -127 ? -127 : q3);
    unsigned int word = (unsigned int)(q0 & 0xFF) | ((unsigned int)(q1 & 0xFF) << 8) |
                        ((unsigned int)(q2 & 0xFF) << 16) | ((unsigned int)(q3 & 0xFF) << 24);
    int kc = k0 >> 6, kk = k0 & 63;
    int lane = (row & 15) | ((kk >> 4) << 4);
    int j0 = kk & 15;
    size_t idx = ((size_t)(row >> 4) * 16 + kc) * 1024 + lane * 16 + j0;
    *(unsigned int*)(dst + idx) = word;
}

// ---------------- approx sim GEMM (i8): barrier-free K-loop, frags direct from global ----------------
// 128x128 block tile, 64x64/wave, mfma_i32_16x16x64_i8 (2x bf16 rate; 64 FLOP/B fabric intensity).
// Per-wave: per K-step(64) loads 4 A-frags + 4 B-frags (16 B/lane each) for 16 MFMA.
// Swizzle: xcd = lin&7 serves cols [colBase + xcd*perX*128, ...) -> B slice L2-resident per XCD.
__global__ __launch_bounds__(256, 3) void gemm1_kernel(const unsigned char* __restrict__ Xq,
                                                       const unsigned char* __restrict__ Wq,
                                                       const float* __restrict__ SA,
                                                       const float* __restrict__ RKS,
                                                       unsigned long long* __restrict__ packed,
                                                       unsigned int* __restrict__ count,
                                                       ushort* __restrict__ candCol,
                                                       int colBase, int perX) {
    __shared__ unsigned long long red[128][2];
    __shared__ float gthr[128];

    const int tid = threadIdx.x;
    const int l = tid & 63;
    const int wave = tid >> 6;
    const int wy = wave >> 1, wx = wave & 1;   // wave tile: 64 rows x 64 cols
    const int lin = blockIdx.x;
    const int x = lin & 7;
    const int j = lin >> 3;
    const int rt = j / perX;
    const int ctl = x * perX + (j - rt * perX);
    const int rowBase = rt * 128;
    const int cwLocal = ctl * 128;

    i32x4 acc[4][4];
#pragma unroll
    for (int mt = 0; mt < 4; ++mt)
#pragma unroll
        for (int nt = 0; nt < 4; ++nt) acc[mt][nt] = (i32x4)0;

    // byte bases; frag(t, kc) = base + t*16384 + kc*1024
    const unsigned char* Ab = Xq + (size_t)(rt * 8 + wy * 4) * 16384 + l * 16;
    const unsigned char* Bb = Wq + (size_t)(colBase / 16 + ctl * 8 + wx * 4) * 16384 + l * 16;

    i32x4 a0[4], b0[4], a1[4], b1[4];
#pragma unroll
    for (int t = 0; t < 4; ++t) {
        a0[t] = *(const i32x4*)(Ab + t * 16384);
        b0[t] = *(const i32x4*)(Bb + t * 16384);
    }

    for (int kc = 0; kc < 16; kc += 2) {
        if (kc + 1 < 16) {
#pragma unroll
            for (int t = 0; t < 4; ++t) {
                a1[t] = *(const i32x4*)(Ab + t * 16384 + (kc + 1) * 1024);
                b1[t] = *(const i32x4*)(Bb + t * 16384 + (kc + 1) * 1024);
            }
        }
#pragma unroll
        for (int nt = 0; nt < 4; ++nt)
#pragma unroll
            for (int mt = 0; mt < 4; ++mt)
                acc[mt][nt] = __builtin_amdgcn_mfma_i32_16x16x64_i8(a0[mt], b0[nt], acc[mt][nt], 0, 0, 0);
        if (kc + 2 < 16) {
#pragma unroll
            for (int t = 0; t < 4; ++t) {
                a0[t] = *(const i32x4*)(Ab + t * 16384 + (kc + 2) * 1024);
                b0[t] = *(const i32x4*)(Bb + t * 16384 + (kc + 2) * 1024);
            }
        }
#pragma unroll
        for (int nt = 0; nt < 4; ++nt)
#pragma unroll
            for (int mt = 0; mt < 4; ++mt)
                acc[mt][nt] = __builtin_amdgcn_mfma_i32_16x16x64_i8(a1[mt], b1[nt], acc[mt][nt], 0, 0, 0);
    }

    // ---- epilogue stage 1: block-level per-row max -> global running max ----
    const int q = l >> 4, c = l & 15;
    float rk_l[4];
#pragma unroll
    for (int nt = 0; nt < 4; ++nt) rk_l[nt] = RKS[colBase + cwLocal + wx * 64 + nt * 16 + c];
#pragma unroll
    for (int mt = 0; mt < 4; ++mt) {
#pragma unroll
        for (int r = 0; r < 4; ++r) {
            float sa = SA[rowBase + wy * 64 + mt * 16 + q * 4 + r];
            unsigned long long pk = 0;
#pragma unroll
            for (int nt = 0; nt < 4; ++nt) {
                float v = (float)acc[mt][nt][r] * sa * rk_l[nt];
                int col = colBase + cwLocal + wx * 64 + nt * 16 + c;
                unsigned long long p = ((unsigned long long)sortable_key(v) << 32) |
                                       (unsigned long long)(~(unsigned int)col);
                if (p > pk) pk = p;
            }
#pragma unroll
            for (int m = 1; m < 16; m <<= 1) {
                unsigned long long o = __shfl_xor(pk, m, 64);
                if (o > pk) pk = o;
            }
            if (c == 0) red[wy * 64 + mt * 16 + q * 4 + r][wx] = pk;
        }
    }
    __syncthreads();
    if (tid < 128) {
        unsigned long long a = red[tid][0], bb = red[tid][1];
        if (bb > a) a = bb;
        unsigned long long old = atomicMax(packed + (rowBase + tid), a);
        unsigned long long g = (old > a) ? old : a;
        gthr[tid] = unkey((unsigned int)(g >> 32)) - DELTA;
    }
    __syncthreads();
    // ---- epilogue stage 2: append candidates within DELTA of known running max ----
#pragma unroll
    for (int mt = 0; mt < 4; ++mt) {
#pragma unroll
        for (int r = 0; r < 4; ++r) {
            int lrow = wy * 64 + mt * 16 + q * 4 + r;
            float thr = gthr[lrow];
            int grow = rowBase + lrow;
            float sa = SA[grow];
#pragma unroll
            for (int nt = 0; nt < 4; ++nt) {
                float v = (float)acc[mt][nt][r] * sa * rk_l[nt];
                if (v >= thr) {
                    unsigned int slot = atomicAdd(count + grow, 1u);
                    if (slot < NCAND) {
                        int col = colBase + cwLocal + wx * 64 + nt * 16 + c;
                        candCol[(size_t)grow * NCAND + slot] = (ushort)col;
                    }
                }
            }
        }
    }
}

// ---------------- exact fp32 rescore + LN stats (merged) ----------------
__global__ __launch_bounds__(256) void rescore_kernel(const float* __restrict__ X,
                                                      const float* __restrict__ W,
                                                      const float* __restrict__ RK,
                                                      const float* __restrict__ RQ,
                                                      const unsigned int* __restrict__ count,
                                                      const ushort* __restrict__ candCol,
                                                      float* __restrict__ outIdx,
                                                      float* __restrict__ outSim,
                                                      int* __restrict__ idxArr,
                                                      float* __restrict__ MU,
                                                      float* __restrict__ RS) {
    int wave = threadIdx.x >> 6, l = threadIdx.x & 63;
    int row = blockIdx.x * 4 + wave;
    unsigned int n = count[row];
    if (n > NCAND) n = NCAND;
    const float4* X4 = (const float4*)X + (size_t)row * 256;
    unsigned long long best = 0;
    for (unsigned int i = 0; i < n; ++i) {
        int col = (int)candCol[(size_t)row * NCAND + i];
        const float4* W4 = (const float4*)W + (size_t)col * 256;
        float s = 0.f;
#pragma unroll
        for (int jj = 0; jj < 4; ++jj) {
            float4 a = X4[jj * 64 + l];
            float4 b = W4[jj * 64 + l];
            s += a.x * b.x + a.y * b.y + a.z * b.z + a.w * b.w;
        }
#pragma unroll
        for (int m = 32; m >= 1; m >>= 1) s += __shfl_xor(s, m, 64);
        float v = s * RK[col];
        unsigned long long pk = ((unsigned long long)sortable_key(v) << 32) |
                                (unsigned long long)(~(unsigned int)col);
        if (pk > best) best = pk;
    }
    int idx = (int)(~(unsigned int)(best & 0xFFFFFFFFull)) & 0xFFFF;
    const float4* Z4 = (const float4*)W + (size_t)idx * 256;
    float s = 0.f, s2 = 0.f;
#pragma unroll
    for (int jj = 0; jj < 4; ++jj) {
        float4 a = X4[jj * 64 + l];
        float4 z = Z4[jj * 64 + l];
        float4 e;
        e.x = (z.x - a.x) + a.x;
        e.y = (z.y - a.y) + a.y;
        e.z = (z.z - a.z) + a.z;
        e.w = (z.w - a.w) + a.w;
        s  += e.x + e.y + e.z + e.w;
        s2 += e.x * e.x + e.y * e.y + e.z * e.z + e.w * e.w;
    }
#pragma unroll
    for (int m = 32; m >= 1; m >>= 1) {
        s  += __shfl_xor(s, m, 64);
        s2 += __shfl_xor(s2, m, 64);
    }
    if (l == 0) {
        outIdx[row] = (float)idx;
        outSim[row] = unkey((unsigned int)(best >> 32)) * RQ[row];
        idxArr[row] = idx;
        float mean = s * (1.f / D);
        float var  = s2 * (1.f / D) - mean * mean;
        MU[row] = mean;
        RS[row] = rsqrtf(var + 1e-6f);
    }
}

// ---------------- projection GEMM: bf16 3-pass MFMA, LN fused into A staging ----------------
__global__ __launch_bounds__(256, 2) void gemm2_kernel(const float* __restrict__ X,
                                                       const float* __restrict__ W,
                                                       const int* __restrict__ idxArr,
                                                       const float* __restrict__ MU,
                                                       const float* __restrict__ RS,
                                                       const float* __restrict__ gamma,
                                                       const float* __restrict__ beta,
                                                       const float* __restrict__ B,
                                                       float* __restrict__ Out) {
    __shared__ ushort Ah[2][8][64][8];
    __shared__ ushort Al[2][8][64][8];
    __shared__ ushort Bh2[2][8][64][8];
    __shared__ ushort Bl2[2][8][64][8];
    __shared__ float Gs[1024];
    __shared__ float Bt[1024];

    const int tid = threadIdx.x;
    const int l = tid & 63;
    const int wave = tid >> 6;
    const int wy = wave >> 1, wx = wave & 1;
    const int rowBase = blockIdx.y * 128;
    const int nBase   = blockIdx.x * 128;

    *(float4*)&Gs[tid * 4] = *(const float4*)(gamma + tid * 4);
    *(float4*)&Bt[tid * 4] = *(const float4*)(beta + tid * 4);

    f32x4 acc[4][4];
#pragma unroll
    for (int mt = 0; mt < 4; ++mt)
#pragma unroll
        for (int nt = 0; nt < 4; ++nt) acc[mt][nt] = (f32x4)0.f;

    const int srow = tid >> 3, skq = tid & 7;
    const int sn = tid & 127, sdq = tid >> 7;
    int aidx[4];
    float amu[4], ars[4];
#pragma unroll
    for (int i = 0; i < 4; ++i) {
        int grow = rowBase + srow + i * 32;
        aidx[i] = idxArr[grow];
        amu[i] = MU[grow];
        ars[i] = RS[grow];
    }

    __syncthreads();

    float4 pz[4], pxv[4], pbv[4];
#pragma unroll
    for (int i = 0; i < 4; ++i) {
        int col = skq * 4;
        pz[i]  = *(const float4*)(W + (size_t)aidx[i] * D + col);
        pxv[i] = *(const float4*)(X + (size_t)(rowBase + srow + i * 32) * D + col);
    }
#pragma unroll
    for (int i = 0; i < 4; ++i) {
        const float* bp = B + (size_t)((sdq + i * 2) * 4) * D + nBase + sn;
        pbv[i] = {bp[0], bp[D], bp[2 * D], bp[3 * D]};
    }

    for (int kc = 0; kc < 32; ++kc) {
        const int bsel = kc & 1;
#pragma unroll
        for (int i = 0; i < 4; ++i) {
            int row = srow + i * 32;
            int col = kc * 32 + skq * 4;
            float4 z = pz[i], xv = pxv[i];
            float4 g  = *(const float4*)&Gs[col];
            float4 bb = *(const float4*)&Bt[col];
            float4 a;
            a.x = (((z.x - xv.x) + xv.x) - amu[i]) * ars[i] * g.x + bb.x;
            a.y = (((z.y - xv.y) + xv.y) - amu[i]) * ars[i] * g.y + bb.y;
            a.z = (((z.z - xv.z) + xv.z) - amu[i]) * ars[i] * g.z + bb.z;
            a.w = (((z.w - xv.w) + xv.w) - amu[i]) * ars[i] * g.w + bb.w;
            uint2 hw, lw;
            split4(a, hw, lw);
            int tile = row >> 4;
            int lf = (row & 15) | ((skq >> 1) << 4);
            int j0 = (skq & 1) * 4;
            *(uint2*)&Ah[bsel][tile][lf][j0] = hw;
            *(uint2*)&Al[bsel][tile][lf][j0] = lw;
        }
#pragma unroll
        for (int i = 0; i < 4; ++i) {
            int dq = sdq + i * 2;
            uint2 hw, lw;
            split4(pbv[i], hw, lw);
            int tile = sn >> 4;
            int lf = (sn & 15) | ((dq >> 1) << 4);
            int j0 = (dq & 1) * 4;
            *(uint2*)&Bh2[bsel][tile][lf][j0] = hw;
            *(uint2*)&Bl2[bsel][tile][lf][j0] = lw;
        }
        __syncthreads();
        float4 pzn[4], pxvn[4], pbvn[4];
        if (kc < 31) {
#pragma unroll
            for (int i = 0; i < 4; ++i) {
                int col = (kc + 1) * 32 + skq * 4;
                pzn[i]  = *(const float4*)(W + (size_t)aidx[i] * D + col);
                pxvn[i] = *(const float4*)(X + (size_t)(rowBase + srow + i * 32) * D + col);
            }
#pragma unroll
            for (int i = 0; i < 4; ++i) {
                const float* bp = B + (size_t)((kc + 1) * 32 + (sdq + i * 2) * 4) * D + nBase + sn;
                pbvn[i] = {bp[0], bp[D], bp[2 * D], bp[3 * D]};
            }
        }
        bf16x8 fah[4], fal[4];
#pragma unroll
        for (int mt = 0; mt < 4; ++mt) {
            fah[mt] = *(const bf16x8*)&Ah[bsel][wy * 4 + mt][l][0];
            fal[mt] = *(const bf16x8*)&Al[bsel][wy * 4 + mt][l][0];
        }
#pragma unroll
        for (int nt = 0; nt < 4; ++nt) {
            bf16x8 bh = *(const bf16x8*)&Bh2[bsel][wx * 4 + nt][l][0];
            bf16x8 bl = *(const bf16x8*)&Bl2[bsel][wx * 4 + nt][l][0];
#pragma unroll
            for (int mt = 0; mt < 4; ++mt) {
                acc[mt][nt] = __builtin_amdgcn_mfma_f32_16x16x32_bf16(fah[mt], bh, acc[mt][nt], 0, 0, 0);
                acc[mt][nt] = __builtin_amdgcn_mfma_f32_16x16x32_bf16(fah[mt], bl, acc[mt][nt], 0, 0, 0);
                acc[mt][nt] = __builtin_amdgcn_mfma_f32_16x16x32_bf16(fal[mt], bh, acc[mt][nt], 0, 0, 0);
            }
        }
        if (kc < 31) {
#pragma unroll
            for (int i = 0; i < 4; ++i) {
                pz[i] = pzn[i]; pxv[i] = pxvn[i]; pbv[i] = pbvn[i];
            }
        }
    }

    const int q = l >> 4, c = l & 15;
#pragma unroll
    for (int mt = 0; mt < 4; ++mt)
#pragma unroll
        for (int nt = 0; nt < 4; ++nt)
#pragma unroll
            for (int r = 0; r < 4; ++r) {
                int grow = rowBase + wy * 64 + mt * 16 + q * 4 + r;
                int gcol = nBase + wx * 64 + nt * 16 + c;
                Out[(size_t)grow * D + gcol] = acc[mt][nt][r];
            }
}

extern "C" void kernel_launch(void* const* d_in, const int* in_sizes, int n_in,
                              void* d_out, int out_size, void* d_ws, size_t ws_size,
                              hipStream_t stream) {
    const float* X     = (const float*)d_in[0];
    const float* W     = (const float*)d_in[1];
    const float* gamma = (const float*)d_in[2];
    const float* beta  = (const float*)d_in[3];
    const float* OW    = (const float*)d_in[4];

    float* out    = (float*)d_out;
    float* outIdx = out;
    float* outSim = out + NROWS;
    float* outO   = out + 2 * NROWS;

    // scratch carved from the 32 MB outO region (all consumed before gemm2 writes it):
    //   Xq8 8 MB | Wq8 16 MB | candCol u16 4 MB | count 32 KB | SA 32 KB | SB 64 KB | RKS 64 KB
    unsigned char* Xq8 = (unsigned char*)outO;
    unsigned char* Wq8 = Xq8 + (size_t)NROWS * D;
    ushort* candCol = (ushort*)(Wq8 + (size_t)V * D);
    unsigned int* count = (unsigned int*)(candCol + (size_t)NROWS * NCAND);
    float* SA  = (float*)(count + NROWS);
    float* SB  = SA + NROWS;
    float* RKS = SB + V;

    // workspace — ~320 KB
    unsigned long long* packed = (unsigned long long*)d_ws;
    float* RK     = (float*)(packed + NROWS);
    float* RQ     = RK + V;
    float* MU     = RQ + NROWS;
    float* RS     = MU + NROWS;
    int*   idxArr = (int*)(RS + NROWS);

    hipLaunchKernelGGL(prep_kernel, dim3((V + NROWS) / 4), dim3(256), 0, stream,
                       W, X, RK, RQ, SA, SB, RKS, packed, count);
    hipLaunchKernelGGL(pack_i8_kernel, dim3(NROWS), dim3(256), 0, stream, X, SA, Xq8);
    hipLaunchKernelGGL(pack_i8_kernel, dim3(V), dim3(256), 0, stream, W, SB, Wq8);

    // 2 column chunks of 8192 keep the cross-chunk running-max head start (bounds rescore work)
    for (int ch = 0; ch < 2; ++ch) {
        int colBase = ch * 8192;
        int perX = (8192 / 128) / 8;   // 8 col-tiles per XCD
        hipLaunchKernelGGL(gemm1_kernel, dim3((NROWS / 128) * (8192 / 128)), dim3(256), 0, stream,
                           Xq8, Wq8, SA, RKS, packed, count, candCol, colBase, perX);
    }

    hipLaunchKernelGGL(rescore_kernel, dim3(NROWS / 4), dim3(256), 0, stream,
                       X, W, RK, RQ, count, candCol, outIdx, outSim, idxArr, MU, RS);
    hipLaunchKernelGGL(gemm2_kernel, dim3(D / 128, NROWS / 128), dim3(256), 0, stream,
                       X, W, idxArr, MU, RS, gamma, beta, OW, outO);
}

// Round 5
// 537.507 us; speedup vs baseline: 1.2064x; 1.0864x over previous
//
#include <hip/hip_runtime.h>
#include <math.h>

#define D 1024
#define V 16384
#define NROWS 8192
#define NCAND 256
#define DELTA 0.15f

typedef __bf16 bf16_t;
typedef bf16_t bf16x8 __attribute__((ext_vector_type(8)));
typedef float f32x4 __attribute__((ext_vector_type(4)));
typedef int i32x4 __attribute__((ext_vector_type(4)));

__device__ __forceinline__ unsigned int sortable_key(float v) {
    unsigned int b = __float_as_uint(v);
    return (b & 0x80000000u) ? ~b : (b | 0x80000000u);
}
__device__ __forceinline__ float unkey(unsigned int key) {
    unsigned int b = (key & 0x80000000u) ? (key & 0x7FFFFFFFu) : ~key;
    return __uint_as_float(b);
}
__device__ __forceinline__ void split4(float4 v, uint2& hw, uint2& lw) {
    unsigned int u0 = __float_as_uint(v.x), u1 = __float_as_uint(v.y);
    unsigned int u2 = __float_as_uint(v.z), u3 = __float_as_uint(v.w);
    float l0 = v.x - __uint_as_float(u0 & 0xFFFF0000u);
    float l1 = v.y - __uint_as_float(u1 & 0xFFFF0000u);
    float l2 = v.z - __uint_as_float(u2 & 0xFFFF0000u);
    float l3 = v.w - __uint_as_float(u3 & 0xFFFF0000u);
    hw.x = (u0 >> 16) | (u1 & 0xFFFF0000u);
    hw.y = (u2 >> 16) | (u3 & 0xFFFF0000u);
    lw.x = (__float_as_uint(l0) >> 16) | (__float_as_uint(l1) & 0xFFFF0000u);
    lw.y = (__float_as_uint(l2) >> 16) | (__float_as_uint(l3) & 0xFFFF0000u);
}

// async 16B global->LDS copy (per-lane global addr; LDS dest = wave-uniform base + lane*16)
__device__ __forceinline__ void gload16(const unsigned char* g, unsigned char* s) {
    __builtin_amdgcn_global_load_lds((const __attribute__((address_space(1))) void*)g,
                                     (__attribute__((address_space(3))) void*)s,
                                     16, 0, 0);
}

// ---------------- merged: row L2-norms + row amax (for i8 scales) of W and X ----------------
__global__ __launch_bounds__(256) void prep_kernel(const float* __restrict__ W,
                                                   const float* __restrict__ X,
                                                   float* __restrict__ RK,
                                                   float* __restrict__ RQ,
                                                   float* __restrict__ SA,
                                                   float* __restrict__ SB,
                                                   float* __restrict__ RKS,
                                                   unsigned long long* __restrict__ packed,
                                                   unsigned int* __restrict__ count) {
    int tid = threadIdx.x;
    int row = blockIdx.x * 4 + (tid >> 6);
    int lane = tid & 63;
    const float* src = (row < V) ? (W + (size_t)row * D) : (X + (size_t)(row - V) * D);
    const float4* p = (const float4*)src;
    float ss = 0.f, am = 0.f;
#pragma unroll
    for (int i = 0; i < 4; ++i) {
        float4 v = p[lane + 64 * i];
        ss += v.x * v.x + v.y * v.y + v.z * v.z + v.w * v.w;
        am = fmaxf(am, fmaxf(fmaxf(fabsf(v.x), fabsf(v.y)), fmaxf(fabsf(v.z), fabsf(v.w))));
    }
#pragma unroll
    for (int m = 32; m >= 1; m >>= 1) {
        ss += __shfl_xor(ss, m, 64);
        am = fmaxf(am, __shfl_xor(am, m, 64));
    }
    if (lane == 0) {
        float rk = rsqrtf(fmaxf(ss, 1e-12f));
        float s = am * (1.f / 127.f);
        if (row < V) {
            RK[row] = rk;
            SB[row] = s;
            RKS[row] = rk * s;
        } else {
            RQ[row - V] = rk;
            SA[row - V] = s;
            packed[row - V] = 0ull;
            count[row - V] = 0u;
        }
    }
}

// ---------------- quantize rows into MFMA-fragment-packed i8 (16x16x64 layout) ----------------
// element (row, k): unit = (row>>4)*16 + (k>>6); lane = (row&15) | (((k&63)>>4)<<4); byte j = k&15
// unit is 1024 bytes = 64 lanes x 16 B (linear per-lane 16B fragments).
__global__ __launch_bounds__(256) void pack_i8_kernel(const float* __restrict__ src,
                                                      const float* __restrict__ S,
                                                      unsigned char* __restrict__ dst) {
    int tid = threadIdx.x;
    int row = blockIdx.x;
    int k0 = tid * 4;
    float4 v = *((const float4*)(src + (size_t)row * D) + tid);
    float s = S[row];
    float inv = (s > 0.f) ? (1.f / s) : 0.f;
    int q0 = (int)rintf(v.x * inv), q1 = (int)rintf(v.y * inv);
    int q2 = (int)rintf(v.z * inv), q3 = (int)rintf(v.w * inv);
    q0 = q0 > 127 ? 127 : (q0 < -127 ? -127 : q0);
    q1 = q1 > 127 ? 127 : (q1 < -127 ? -127 : q1);
    q2 = q2 > 127 ? 127 : (q2 < -127 ? -127 : q2);
    q3 = q3 > 127 ? 127 : (q3 < -127 ? -127 : q3);
    unsigned int word = (unsigned int)(q0 & 0xFF) | ((unsigned int)(q1 & 0xFF) << 8) |
                        ((unsigned int)(q2 & 0xFF) << 16) | ((unsigned int)(q3 & 0xFF) << 24);
    int kc = k0 >> 6, kk = k0 & 63;
    int lane = (row & 15) | ((kk >> 4) << 4);
    int j0 = kk & 15;
    size_t idx = ((size_t)(row >> 4) * 16 + kc) * 1024 + lane * 16 + j0;
    *(unsigned int*)(dst + idx) = word;
}

// ---------------- approx sim GEMM (i8): m97-structure — 128x128 tile, 16KB LDS, 4 blocks/CU ----------------
// BK=64 (one i8 k-chunk). Per step: 16x global_load_lds (A 8KB + B 8KB), __syncthreads,
// 8x ds_read_b128/wave, 16 MFMA(16x16x64_i8)/wave, __syncthreads. Latency hiding comes from
// 4 co-resident blocks/CU (m114 implicit wave-level overlap), not from in-block pipelining.
// Fragment-packed global layout keeps gload_lds dests linear and ds_reads conflict-free.
__global__ __launch_bounds__(256, 4) void gemm1_kernel(const unsigned char* __restrict__ Xq,
                                                       const unsigned char* __restrict__ Wq,
                                                       const float* __restrict__ SA,
                                                       const float* __restrict__ RKS,
                                                       unsigned long long* __restrict__ packed,
                                                       unsigned int* __restrict__ count,
                                                       ushort* __restrict__ candCol,
                                                       int colBase, int perX) {
    __shared__ __align__(16) unsigned char lds[16384];
    __shared__ unsigned long long red[128][2];
    __shared__ float gthr[128];

    const int tid = threadIdx.x;
    const int l = tid & 63;
    const int w = tid >> 6;                 // 0..3
    const int wy = w >> 1, wx = w & 1;      // wave tile: 64 rows x 64 cols
    const int lin = blockIdx.x;
    const int x = lin & 7;
    const int j = lin >> 3;
    const int rt = j / perX;
    const int ctl = x * perX + (j - rt * perX);
    const int rowBase = rt * 128;
    const int cwLocal = ctl * 128;

    i32x4 acc[4][4];
#pragma unroll
    for (int mt = 0; mt < 4; ++mt)
#pragma unroll
        for (int nt = 0; nt < 4; ++nt) acc[mt][nt] = (i32x4)0;

    // unit bases: A row-groups rt*8..rt*8+7; B row-groups colBase/16 + ctl*8 ..+7
    const unsigned char* As = Xq + ((size_t)(rt * 8) * 16) * 1024;
    const unsigned char* Bs = Wq + ((size_t)((colBase >> 4) + ctl * 8) * 16) * 1024;

#pragma unroll 1
    for (int kc = 0; kc < 16; ++kc) {
        // stage: wave w loads A units {2w,2w+1} and B units {2w,2w+1} (1KB each)
#pragma unroll
        for (int i = 0; i < 2; ++i) {
            int u = 2 * w + i;
            gload16(As + ((size_t)(u * 16 + kc)) * 1024 + l * 16, lds + u * 1024);
            gload16(Bs + ((size_t)(u * 16 + kc)) * 1024 + l * 16, lds + 8192 + u * 1024);
        }
        __syncthreads();          // compiler drains vmcnt(0) here — staged data visible
        i32x4 af[4], bf[4];
#pragma unroll
        for (int mi = 0; mi < 4; ++mi)
            af[mi] = *(const i32x4*)(lds + (wy * 4 + mi) * 1024 + l * 16);
#pragma unroll
        for (int nt = 0; nt < 4; ++nt)
            bf[nt] = *(const i32x4*)(lds + 8192 + (wx * 4 + nt) * 1024 + l * 16);
#pragma unroll
        for (int nt = 0; nt < 4; ++nt)
#pragma unroll
            for (int mi = 0; mi < 4; ++mi)
                acc[mi][nt] = __builtin_amdgcn_mfma_i32_16x16x64_i8(af[mi], bf[nt], acc[mi][nt], 0, 0, 0);
        __syncthreads();          // all waves done reading before next overwrite
    }

    // ---- epilogue stage 1: block-level per-row max -> global running max ----
    const int q = l >> 4, c = l & 15;
    float rk_l[4];
#pragma unroll
    for (int nt = 0; nt < 4; ++nt) rk_l[nt] = RKS[colBase + cwLocal + wx * 64 + nt * 16 + c];
#pragma unroll
    for (int mt = 0; mt < 4; ++mt) {
#pragma unroll
        for (int r = 0; r < 4; ++r) {
            float sa = SA[rowBase + wy * 64 + mt * 16 + q * 4 + r];
            unsigned long long pk = 0;
#pragma unroll
            for (int nt = 0; nt < 4; ++nt) {
                float v = (float)acc[mt][nt][r] * sa * rk_l[nt];
                int col = colBase + cwLocal + wx * 64 + nt * 16 + c;
                unsigned long long p = ((unsigned long long)sortable_key(v) << 32) |
                                       (unsigned long long)(~(unsigned int)col);
                if (p > pk) pk = p;
            }
#pragma unroll
            for (int m = 1; m < 16; m <<= 1) {
                unsigned long long o = __shfl_xor(pk, m, 64);
                if (o > pk) pk = o;
            }
            if (c == 0) red[wy * 64 + mt * 16 + q * 4 + r][wx] = pk;
        }
    }
    __syncthreads();
    if (tid < 128) {
        unsigned long long a = red[tid][0], bb = red[tid][1];
        if (bb > a) a = bb;
        unsigned long long old = atomicMax(packed + (rowBase + tid), a);
        unsigned long long g = (old > a) ? old : a;
        gthr[tid] = unkey((unsigned int)(g >> 32)) - DELTA;
    }
    __syncthreads();
    // ---- epilogue stage 2: append candidates within DELTA of known running max ----
#pragma unroll
    for (int mt = 0; mt < 4; ++mt) {
#pragma unroll
        for (int r = 0; r < 4; ++r) {
            int lrow = wy * 64 + mt * 16 + q * 4 + r;
            float thr = gthr[lrow];
            int grow = rowBase + lrow;
            float sa = SA[grow];
#pragma unroll
            for (int nt = 0; nt < 4; ++nt) {
                float v = (float)acc[mt][nt][r] * sa * rk_l[nt];
                if (v >= thr) {
                    unsigned int slot = atomicAdd(count + grow, 1u);
                    if (slot < NCAND) {
                        int col = colBase + cwLocal + wx * 64 + nt * 16 + c;
                        candCol[(size_t)grow * NCAND + slot] = (ushort)col;
                    }
                }
            }
        }
    }
}

// ---------------- exact fp32 rescore + LN stats (merged) ----------------
__global__ __launch_bounds__(256) void rescore_kernel(const float* __restrict__ X,
                                                      const float* __restrict__ W,
                                                      const float* __restrict__ RK,
                                                      const float* __restrict__ RQ,
                                                      const unsigned int* __restrict__ count,
                                                      const ushort* __restrict__ candCol,
                                                      float* __restrict__ outIdx,
                                                      float* __restrict__ outSim,
                                                      int* __restrict__ idxArr,
                                                      float* __restrict__ MU,
                                                      float* __restrict__ RS) {
    int wave = threadIdx.x >> 6, l = threadIdx.x & 63;
    int row = blockIdx.x * 4 + wave;
    unsigned int n = count[row];
    if (n > NCAND) n = NCAND;
    const float4* X4 = (const float4*)X + (size_t)row * 256;
    unsigned long long best = 0;
    for (unsigned int i = 0; i < n; ++i) {
        int col = (int)candCol[(size_t)row * NCAND + i];
        const float4* W4 = (const float4*)W + (size_t)col * 256;
        float s = 0.f;
#pragma unroll
        for (int jj = 0; jj < 4; ++jj) {
            float4 a = X4[jj * 64 + l];
            float4 b = W4[jj * 64 + l];
            s += a.x * b.x + a.y * b.y + a.z * b.z + a.w * b.w;
        }
#pragma unroll
        for (int m = 32; m >= 1; m >>= 1) s += __shfl_xor(s, m, 64);
        float v = s * RK[col];
        unsigned long long pk = ((unsigned long long)sortable_key(v) << 32) |
                                (unsigned long long)(~(unsigned int)col);
        if (pk > best) best = pk;
    }
    int idx = (int)(~(unsigned int)(best & 0xFFFFFFFFull)) & 0xFFFF;
    const float4* Z4 = (const float4*)W + (size_t)idx * 256;
    float s = 0.f, s2 = 0.f;
#pragma unroll
    for (int jj = 0; jj < 4; ++jj) {
        float4 a = X4[jj * 64 + l];
        float4 z = Z4[jj * 64 + l];
        float4 e;
        e.x = (z.x - a.x) + a.x;
        e.y = (z.y - a.y) + a.y;
        e.z = (z.z - a.z) + a.z;
        e.w = (z.w - a.w) + a.w;
        s  += e.x + e.y + e.z + e.w;
        s2 += e.x * e.x + e.y * e.y + e.z * e.z + e.w * e.w;
    }
#pragma unroll
    for (int m = 32; m >= 1; m >>= 1) {
        s  += __shfl_xor(s, m, 64);
        s2 += __shfl_xor(s2, m, 64);
    }
    if (l == 0) {
        outIdx[row] = (float)idx;
        outSim[row] = unkey((unsigned int)(best >> 32)) * RQ[row];
        idxArr[row] = idx;
        float mean = s * (1.f / D);
        float var  = s2 * (1.f / D) - mean * mean;
        MU[row] = mean;
        RS[row] = rsqrtf(var + 1e-6f);
    }
}

// ---------------- projection GEMM: bf16 3-pass MFMA, LN fused into A staging ----------------
__global__ __launch_bounds__(256, 2) void gemm2_kernel(const float* __restrict__ X,
                                                       const float* __restrict__ W,
                                                       const int* __restrict__ idxArr,
                                                       const float* __restrict__ MU,
                                                       const float* __restrict__ RS,
                                                       const float* __restrict__ gamma,
                                                       const float* __restrict__ beta,
                                                       const float* __restrict__ B,
                                                       float* __restrict__ Out) {
    __shared__ ushort Ah[2][8][64][8];
    __shared__ ushort Al[2][8][64][8];
    __shared__ ushort Bh2[2][8][64][8];
    __shared__ ushort Bl2[2][8][64][8];
    __shared__ float Gs[1024];
    __shared__ float Bt[1024];

    const int tid = threadIdx.x;
    const int l = tid & 63;
    const int wave = tid >> 6;
    const int wy = wave >> 1, wx = wave & 1;
    const int rowBase = blockIdx.y * 128;
    const int nBase   = blockIdx.x * 128;

    *(float4*)&Gs[tid * 4] = *(const float4*)(gamma + tid * 4);
    *(float4*)&Bt[tid * 4] = *(const float4*)(beta + tid * 4);

    f32x4 acc[4][4];
#pragma unroll
    for (int mt = 0; mt < 4; ++mt)
#pragma unroll
        for (int nt = 0; nt < 4; ++nt) acc[mt][nt] = (f32x4)0.f;

    const int srow = tid >> 3, skq = tid & 7;
    const int sn = tid & 127, sdq = tid >> 7;
    int aidx[4];
    float amu[4], ars[4];
#pragma unroll
    for (int i = 0; i < 4; ++i) {
        int grow = rowBase + srow + i * 32;
        aidx[i] = idxArr[grow];
        amu[i] = MU[grow];
        ars[i] = RS[grow];
    }

    __syncthreads();

    float4 pz[4], pxv[4], pbv[4];
#pragma unroll
    for (int i = 0; i < 4; ++i) {
        int col = skq * 4;
        pz[i]  = *(const float4*)(W + (size_t)aidx[i] * D + col);
        pxv[i] = *(const float4*)(X + (size_t)(rowBase + srow + i * 32) * D + col);
    }
#pragma unroll
    for (int i = 0; i < 4; ++i) {
        const float* bp = B + (size_t)((sdq + i * 2) * 4) * D + nBase + sn;
        pbv[i] = {bp[0], bp[D], bp[2 * D], bp[3 * D]};
    }

    for (int kc = 0; kc < 32; ++kc) {
        const int bsel = kc & 1;
#pragma unroll
        for (int i = 0; i < 4; ++i) {
            int row = srow + i * 32;
            int col = kc * 32 + skq * 4;
            float4 z = pz[i], xv = pxv[i];
            float4 g  = *(const float4*)&Gs[col];
            float4 bb = *(const float4*)&Bt[col];
            float4 a;
            a.x = (((z.x - xv.x) + xv.x) - amu[i]) * ars[i] * g.x + bb.x;
            a.y = (((z.y - xv.y) + xv.y) - amu[i]) * ars[i] * g.y + bb.y;
            a.z = (((z.z - xv.z) + xv.z) - amu[i]) * ars[i] * g.z + bb.z;
            a.w = (((z.w - xv.w) + xv.w) - amu[i]) * ars[i] * g.w + bb.w;
            uint2 hw, lw;
            split4(a, hw, lw);
            int tile = row >> 4;
            int lf = (row & 15) | ((skq >> 1) << 4);
            int j0 = (skq & 1) * 4;
            *(uint2*)&Ah[bsel][tile][lf][j0] = hw;
            *(uint2*)&Al[bsel][tile][lf][j0] = lw;
        }
#pragma unroll
        for (int i = 0; i < 4; ++i) {
            int dq = sdq + i * 2;
            uint2 hw, lw;
            split4(pbv[i], hw, lw);
            int tile = sn >> 4;
            int lf = (sn & 15) | ((dq >> 1) << 4);
            int j0 = (dq & 1) * 4;
            *(uint2*)&Bh2[bsel][tile][lf][j0] = hw;
            *(uint2*)&Bl2[bsel][tile][lf][j0] = lw;
        }
        __syncthreads();
        float4 pzn[4], pxvn[4], pbvn[4];
        if (kc < 31) {
#pragma unroll
            for (int i = 0; i < 4; ++i) {
                int col = (kc + 1) * 32 + skq * 4;
                pzn[i]  = *(const float4*)(W + (size_t)aidx[i] * D + col);
                pxvn[i] = *(const float4*)(X + (size_t)(rowBase + srow + i * 32) * D + col);
            }
#pragma unroll
            for (int i = 0; i < 4; ++i) {
                const float* bp = B + (size_t)((kc + 1) * 32 + (sdq + i * 2) * 4) * D + nBase + sn;
                pbvn[i] = {bp[0], bp[D], bp[2 * D], bp[3 * D]};
            }
        }
        bf16x8 fah[4], fal[4];
#pragma unroll
        for (int mt = 0; mt < 4; ++mt) {
            fah[mt] = *(const bf16x8*)&Ah[bsel][wy * 4 + mt][l][0];
            fal[mt] = *(const bf16x8*)&Al[bsel][wy * 4 + mt][l][0];
        }
#pragma unroll
        for (int nt = 0; nt < 4; ++nt) {
            bf16x8 bh = *(const bf16x8*)&Bh2[bsel][wx * 4 + nt][l][0];
            bf16x8 bl = *(const bf16x8*)&Bl2[bsel][wx * 4 + nt][l][0];
#pragma unroll
            for (int mt = 0; mt < 4; ++mt) {
                acc[mt][nt] = __builtin_amdgcn_mfma_f32_16x16x32_bf16(fah[mt], bh, acc[mt][nt], 0, 0, 0);
                acc[mt][nt] = __builtin_amdgcn_mfma_f32_16x16x32_bf16(fah[mt], bl, acc[mt][nt], 0, 0, 0);
                acc[mt][nt] = __builtin_amdgcn_mfma_f32_16x16x32_bf16(fal[mt], bh, acc[mt][nt], 0, 0, 0);
            }
        }
        if (kc < 31) {
#pragma unroll
            for (int i = 0; i < 4; ++i) {
                pz[i] = pzn[i]; pxv[i] = pxvn[i]; pbv[i] = pbvn[i];
            }
        }
    }

    const int q = l >> 4, c = l & 15;
#pragma unroll
    for (int mt = 0; mt < 4; ++mt)
#pragma unroll
        for (int nt = 0; nt < 4; ++nt)
#pragma unroll
            for (int r = 0; r < 4; ++r) {
                int grow = rowBase + wy * 64 + mt * 16 + q * 4 + r;
                int gcol = nBase + wx * 64 + nt * 16 + c;
                Out[(size_t)grow * D + gcol] = acc[mt][nt][r];
            }
}

extern "C" void kernel_launch(void* const* d_in, const int* in_sizes, int n_in,
                              void* d_out, int out_size, void* d_ws, size_t ws_size,
                              hipStream_t stream) {
    const float* X     = (const float*)d_in[0];
    const float* W     = (const float*)d_in[1];
    const float* gamma = (const float*)d_in[2];
    const float* beta  = (const float*)d_in[3];
    const float* OW    = (const float*)d_in[4];

    float* out    = (float*)d_out;
    float* outIdx = out;
    float* outSim = out + NROWS;
    float* outO   = out + 2 * NROWS;

    // scratch carved from the 32 MB outO region (all consumed before gemm2 writes it):
    //   Xq8 8 MB | Wq8 16 MB | candCol u16 4 MB | count 32 KB | SA 32 KB | SB 64 KB | RKS 64 KB
    unsigned char* Xq8 = (unsigned char*)outO;
    unsigned char* Wq8 = Xq8 + (size_t)NROWS * D;
    ushort* candCol = (ushort*)(Wq8 + (size_t)V * D);
    unsigned int* count = (unsigned int*)(candCol + (size_t)NROWS * NCAND);
    float* SA  = (float*)(count + NROWS);
    float* SB  = SA + NROWS;
    float* RKS = SB + V;

    // workspace — ~320 KB
    unsigned long long* packed = (unsigned long long*)d_ws;
    float* RK     = (float*)(packed + NROWS);
    float* RQ     = RK + V;
    float* MU     = RQ + NROWS;
    float* RS     = MU + NROWS;
    int*   idxArr = (int*)(RS + NROWS);

    hipLaunchKernelGGL(prep_kernel, dim3((V + NROWS) / 4), dim3(256), 0, stream,
                       W, X, RK, RQ, SA, SB, RKS, packed, count);
    hipLaunchKernelGGL(pack_i8_kernel, dim3(NROWS), dim3(256), 0, stream, X, SA, Xq8);
    hipLaunchKernelGGL(pack_i8_kernel, dim3(V), dim3(256), 0, stream, W, SB, Wq8);

    // 2 column chunks of 8192 keep the cross-chunk running-max head start (bounds rescore work)
    for (int ch = 0; ch < 2; ++ch) {
        int colBase = ch * 8192;
        int perX = (8192 / 128) / 8;   // 8 col-tiles per XCD
        hipLaunchKernelGGL(gemm1_kernel, dim3((NROWS / 128) * (8192 / 128)), dim3(256), 0, stream,
                           Xq8, Wq8, SA, RKS, packed, count, candCol, colBase, perX);
    }

    hipLaunchKernelGGL(rescore_kernel, dim3(NROWS / 4), dim3(256), 0, stream,
                       X, W, RK, RQ, count, candCol, outIdx, outSim, idxArr, MU, RS);
    hipLaunchKernelGGL(gemm2_kernel, dim3(D / 128, NROWS / 128), dim3(256), 0, stream,
                       X, W, idxArr, MU, RS, gamma, beta, OW, outO);
}

// Round 7
// 527.088 us; speedup vs baseline: 1.2303x; 1.0198x over previous
//
#include <hip/hip_runtime.h>
#include <math.h>

#define D 1024
#define V 16384
#define NROWS 8192
#define NCAND 256
#define DELTA 0.15f

typedef __bf16 bf16_t;
typedef bf16_t bf16x8 __attribute__((ext_vector_type(8)));
typedef float f32x4 __attribute__((ext_vector_type(4)));
typedef int i32x4 __attribute__((ext_vector_type(4)));

__device__ __forceinline__ unsigned int sortable_key(float v) {
    unsigned int b = __float_as_uint(v);
    return (b & 0x80000000u) ? ~b : (b | 0x80000000u);
}
__device__ __forceinline__ float unkey(unsigned int key) {
    unsigned int b = (key & 0x80000000u) ? (key & 0x7FFFFFFFu) : ~key;
    return __uint_as_float(b);
}
__device__ __forceinline__ void split4(float4 v, uint2& hw, uint2& lw) {
    unsigned int u0 = __float_as_uint(v.x), u1 = __float_as_uint(v.y);
    unsigned int u2 = __float_as_uint(v.z), u3 = __float_as_uint(v.w);
    float l0 = v.x - __uint_as_float(u0 & 0xFFFF0000u);
    float l1 = v.y - __uint_as_float(u1 & 0xFFFF0000u);
    float l2 = v.z - __uint_as_float(u2 & 0xFFFF0000u);
    float l3 = v.w - __uint_as_float(u3 & 0xFFFF0000u);
    hw.x = (u0 >> 16) | (u1 & 0xFFFF0000u);
    hw.y = (u2 >> 16) | (u3 & 0xFFFF0000u);
    lw.x = (__float_as_uint(l0) >> 16) | (__float_as_uint(l1) & 0xFFFF0000u);
    lw.y = (__float_as_uint(l2) >> 16) | (__float_as_uint(l3) & 0xFFFF0000u);
}

// async 16B global->LDS copy (per-lane global addr; LDS dest = wave-uniform base + lane*16)
__device__ __forceinline__ void gload16(const unsigned char* g, unsigned char* s) {
    __builtin_amdgcn_global_load_lds((const __attribute__((address_space(1))) void*)g,
                                     (__attribute__((address_space(3))) void*)s,
                                     16, 0, 0);
}

// ---------------- merged: row L2-norms + row amax (for i8 scales) of W and X ----------------
__global__ __launch_bounds__(256) void prep_kernel(const float* __restrict__ W,
                                                   const float* __restrict__ X,
                                                   float* __restrict__ RK,
                                                   float* __restrict__ RQ,
                                                   float* __restrict__ SA,
                                                   float* __restrict__ SB,
                                                   float* __restrict__ RKS,
                                                   unsigned long long* __restrict__ packed,
                                                   unsigned int* __restrict__ count) {
    int tid = threadIdx.x;
    int row = blockIdx.x * 4 + (tid >> 6);
    int lane = tid & 63;
    const float* src = (row < V) ? (W + (size_t)row * D) : (X + (size_t)(row - V) * D);
    const float4* p = (const float4*)src;
    float ss = 0.f, am = 0.f;
#pragma unroll
    for (int i = 0; i < 4; ++i) {
        float4 v = p[lane + 64 * i];
        ss += v.x * v.x + v.y * v.y + v.z * v.z + v.w * v.w;
        am = fmaxf(am, fmaxf(fmaxf(fabsf(v.x), fabsf(v.y)), fmaxf(fabsf(v.z), fabsf(v.w))));
    }
#pragma unroll
    for (int m = 32; m >= 1; m >>= 1) {
        ss += __shfl_xor(ss, m, 64);
        am = fmaxf(am, __shfl_xor(am, m, 64));
    }
    if (lane == 0) {
        float rk = rsqrtf(fmaxf(ss, 1e-12f));
        float s = am * (1.f / 127.f);
        if (row < V) {
            RK[row] = rk;
            SB[row] = s;
            RKS[row] = rk * s;
        } else {
            RQ[row - V] = rk;
            SA[row - V] = s;
            packed[row - V] = 0ull;
            count[row - V] = 0u;
        }
    }
}

// ---------------- quantize rows into MFMA-fragment-packed i8 (16x16x64 layout) ----------------
// element (row, k): unit = (row>>4)*16 + (k>>6); lane = (row&15) | (((k&63)>>4)<<4); byte j = k&15
// unit is 1024 bytes = 64 lanes x 16 B (linear per-lane 16B fragments).
__global__ __launch_bounds__(256) void pack_i8_kernel(const float* __restrict__ src,
                                                      const float* __restrict__ S,
                                                      unsigned char* __restrict__ dst) {
    int tid = threadIdx.x;
    int row = blockIdx.x;
    int k0 = tid * 4;
    float4 v = *((const float4*)(src + (size_t)row * D) + tid);
    float s = S[row];
    float inv = (s > 0.f) ? (1.f / s) : 0.f;
    int q0 = (int)rintf(v.x * inv), q1 = (int)rintf(v.y * inv);
    int q2 = (int)rintf(v.z * inv), q3 = (int)rintf(v.w * inv);
    q0 = q0 > 127 ? 127 : (q0 < -127 ? -127 : q0);
    q1 = q1 > 127 ? 127 : (q1 < -127 ? -127 : q1);
    q2 = q2 > 127 ? 127 : (q2 < -127 ? -127 : q2);
    q3 = q3 > 127 ? 127 : (q3 < -127 ? -127 : q3);
    unsigned int word = (unsigned int)(q0 & 0xFF) | ((unsigned int)(q1 & 0xFF) << 8) |
                        ((unsigned int)(q2 & 0xFF) << 16) | ((unsigned int)(q3 & 0xFF) << 24);
    int kc = k0 >> 6, kk = k0 & 63;
    int lane = (row & 15) | ((kk >> 4) << 4);
    int j0 = kk & 15;
    size_t idx = ((size_t)(row >> 4) * 16 + kc) * 1024 + lane * 16 + j0;
    *(unsigned int*)(dst + idx) = word;
}

// ---------------- approx sim GEMM (i8): m97-structure, BK=128 — 128x128 tile, 32KB LDS, 4 blocks/CU ----------------
// Per sync-pair: stage 32KB (A 16KB + B 16KB, two k-chunks) via 32x global_load_lds, __syncthreads
// (drains vmcnt), then two register-sequential sub-blocks {8x ds_read_b128, 16x mfma_i32_16x16x64_i8},
// __syncthreads. Halves barrier/drain events per MFMA vs BK=64 (R5's residual overhead).
// Latency hiding across blocks: 4 co-resident blocks/CU (launch_bounds caps VGPR at 128).
// Fragment-packed global layout keeps gload_lds dests linear and ds_reads conflict-free.
__global__ __launch_bounds__(256, 4) void gemm1_kernel(const unsigned char* __restrict__ Xq,
                                                       const unsigned char* __restrict__ Wq,
                                                       const float* __restrict__ SA,
                                                       const float* __restrict__ RKS,
                                                       unsigned long long* __restrict__ packed,
                                                       unsigned int* __restrict__ count,
                                                       ushort* __restrict__ candCol,
                                                       int colBase, int perX) {
    __shared__ __align__(16) unsigned char lds[32768];
    __shared__ unsigned long long red[128][2];
    __shared__ float gthr[128];

    const int tid = threadIdx.x;
    const int l = tid & 63;
    const int w = tid >> 6;                 // 0..3
    const int wy = w >> 1, wx = w & 1;      // wave tile: 64 rows x 64 cols
    const int lin = blockIdx.x;
    const int x = lin & 7;
    const int j = lin >> 3;
    const int rt = j / perX;
    const int ctl = x * perX + (j - rt * perX);
    const int rowBase = rt * 128;
    const int cwLocal = ctl * 128;

    i32x4 acc[4][4];
#pragma unroll
    for (int mt = 0; mt < 4; ++mt)
#pragma unroll
        for (int nt = 0; nt < 4; ++nt) acc[mt][nt] = (i32x4)0;

    // unit bases: A row-groups rt*8..rt*8+7; B row-groups colBase/16 + ctl*8 ..+7
    const unsigned char* As = Xq + ((size_t)(rt * 8) * 16) * 1024;
    const unsigned char* Bs = Wq + ((size_t)((colBase >> 4) + ctl * 8) * 16) * 1024;

    // LDS layout: A unit (rgroup u, kchunk jj) at (u*2+jj)*1024; B at 16384 + (u*2+jj)*1024.
#pragma unroll 1
    for (int kc = 0; kc < 16; kc += 2) {
        // stage: wave w loads A units {2w,2w+1} x {kc,kc+1} and B units likewise (8 gloads/wave)
#pragma unroll
        for (int i = 0; i < 2; ++i) {
            int u = 2 * w + i;
#pragma unroll
            for (int jj = 0; jj < 2; ++jj) {
                gload16(As + ((size_t)(u * 16 + kc + jj)) * 1024 + l * 16,
                        lds + (u * 2 + jj) * 1024);
                gload16(Bs + ((size_t)(u * 16 + kc + jj)) * 1024 + l * 16,
                        lds + 16384 + (u * 2 + jj) * 1024);
            }
        }
        __syncthreads();          // compiler drains vmcnt(0) here — staged data visible
#pragma unroll
        for (int jj = 0; jj < 2; ++jj) {
            i32x4 af[4], bf[4];
#pragma unroll
            for (int mi = 0; mi < 4; ++mi)
                af[mi] = *(const i32x4*)(lds + ((wy * 4 + mi) * 2 + jj) * 1024 + l * 16);
#pragma unroll
            for (int nt = 0; nt < 4; ++nt)
                bf[nt] = *(const i32x4*)(lds + 16384 + ((wx * 4 + nt) * 2 + jj) * 1024 + l * 16);
#pragma unroll
            for (int nt = 0; nt < 4; ++nt)
#pragma unroll
                for (int mi = 0; mi < 4; ++mi)
                    acc[mi][nt] = __builtin_amdgcn_mfma_i32_16x16x64_i8(af[mi], bf[nt], acc[mi][nt], 0, 0, 0);
        }
        __syncthreads();          // all waves done reading before next overwrite
    }

    // ---- epilogue stage 1: block-level per-row max -> global running max ----
    const int q = l >> 4, c = l & 15;
    float rk_l[4];
#pragma unroll
    for (int nt = 0; nt < 4; ++nt) rk_l[nt] = RKS[colBase + cwLocal + wx * 64 + nt * 16 + c];
#pragma unroll
    for (int mt = 0; mt < 4; ++mt) {
#pragma unroll
        for (int r = 0; r < 4; ++r) {
            float sa = SA[rowBase + wy * 64 + mt * 16 + q * 4 + r];
            unsigned long long pk = 0;
#pragma unroll
            for (int nt = 0; nt < 4; ++nt) {
                float v = (float)acc[mt][nt][r] * sa * rk_l[nt];
                int col = colBase + cwLocal + wx * 64 + nt * 16 + c;
                unsigned long long p = ((unsigned long long)sortable_key(v) << 32) |
                                       (unsigned long long)(~(unsigned int)col);
                if (p > pk) pk = p;
            }
#pragma unroll
            for (int m = 1; m < 16; m <<= 1) {
                unsigned long long o = __shfl_xor(pk, m, 64);
                if (o > pk) pk = o;
            }
            if (c == 0) red[wy * 64 + mt * 16 + q * 4 + r][wx] = pk;
        }
    }
    __syncthreads();
    if (tid < 128) {
        unsigned long long a = red[tid][0], bb = red[tid][1];
        if (bb > a) a = bb;
        unsigned long long old = atomicMax(packed + (rowBase + tid), a);
        unsigned long long g = (old > a) ? old : a;
        gthr[tid] = unkey((unsigned int)(g >> 32)) - DELTA;
    }
    __syncthreads();
    // ---- epilogue stage 2: append candidates within DELTA of known running max ----
#pragma unroll
    for (int mt = 0; mt < 4; ++mt) {
#pragma unroll
        for (int r = 0; r < 4; ++r) {
            int lrow = wy * 64 + mt * 16 + q * 4 + r;
            float thr = gthr[lrow];
            int grow = rowBase + lrow;
            float sa = SA[grow];
#pragma unroll
            for (int nt = 0; nt < 4; ++nt) {
                float v = (float)acc[mt][nt][r] * sa * rk_l[nt];
                if (v >= thr) {
                    unsigned int slot = atomicAdd(count + grow, 1u);
                    if (slot < NCAND) {
                        int col = colBase + cwLocal + wx * 64 + nt * 16 + c;
                        candCol[(size_t)grow * NCAND + slot] = (ushort)col;
                    }
                }
            }
        }
    }
}

// ---------------- exact fp32 rescore + LN stats (merged) ----------------
__global__ __launch_bounds__(256) void rescore_kernel(const float* __restrict__ X,
                                                      const float* __restrict__ W,
                                                      const float* __restrict__ RK,
                                                      const float* __restrict__ RQ,
                                                      const unsigned int* __restrict__ count,
                                                      const ushort* __restrict__ candCol,
                                                      float* __restrict__ outIdx,
                                                      float* __restrict__ outSim,
                                                      int* __restrict__ idxArr,
                                                      float* __restrict__ MU,
                                                      float* __restrict__ RS) {
    int wave = threadIdx.x >> 6, l = threadIdx.x & 63;
    int row = blockIdx.x * 4 + wave;
    unsigned int n = count[row];
    if (n > NCAND) n = NCAND;
    const float4* X4 = (const float4*)X + (size_t)row * 256;
    unsigned long long best = 0;
    for (unsigned int i = 0; i < n; ++i) {
        int col = (int)candCol[(size_t)row * NCAND + i];
        const float4* W4 = (const float4*)W + (size_t)col * 256;
        float s = 0.f;
#pragma unroll
        for (int jj = 0; jj < 4; ++jj) {
            float4 a = X4[jj * 64 + l];
            float4 b = W4[jj * 64 + l];
            s += a.x * b.x + a.y * b.y + a.z * b.z + a.w * b.w;
        }
#pragma unroll
        for (int m = 32; m >= 1; m >>= 1) s += __shfl_xor(s, m, 64);
        float v = s * RK[col];
        unsigned long long pk = ((unsigned long long)sortable_key(v) << 32) |
                                (unsigned long long)(~(unsigned int)col);
        if (pk > best) best = pk;
    }
    int idx = (int)(~(unsigned int)(best & 0xFFFFFFFFull)) & 0xFFFF;
    const float4* Z4 = (const float4*)W + (size_t)idx * 256;
    float s = 0.f, s2 = 0.f;
#pragma unroll
    for (int jj = 0; jj < 4; ++jj) {
        float4 a = X4[jj * 64 + l];
        float4 z = Z4[jj * 64 + l];
        float4 e;
        e.x = (z.x - a.x) + a.x;
        e.y = (z.y - a.y) + a.y;
        e.z = (z.z - a.z) + a.z;
        e.w = (z.w - a.w) + a.w;
        s  += e.x + e.y + e.z + e.w;
        s2 += e.x * e.x + e.y * e.y + e.z * e.z + e.w * e.w;
    }
#pragma unroll
    for (int m = 32; m >= 1; m >>= 1) {
        s  += __shfl_xor(s, m, 64);
        s2 += __shfl_xor(s2, m, 64);
    }
    if (l == 0) {
        outIdx[row] = (float)idx;
        outSim[row] = unkey((unsigned int)(best >> 32)) * RQ[row];
        idxArr[row] = idx;
        float mean = s * (1.f / D);
        float var  = s2 * (1.f / D) - mean * mean;
        MU[row] = mean;
        RS[row] = rsqrtf(var + 1e-6f);
    }
}

// ---------------- projection GEMM: bf16 3-pass MFMA, LN fused into A staging ----------------
__global__ __launch_bounds__(256, 2) void gemm2_kernel(const float* __restrict__ X,
                                                       const float* __restrict__ W,
                                                       const int* __restrict__ idxArr,
                                                       const float* __restrict__ MU,
                                                       const float* __restrict__ RS,
                                                       const float* __restrict__ gamma,
                                                       const float* __restrict__ beta,
                                                       const float* __restrict__ B,
                                                       float* __restrict__ Out) {
    __shared__ ushort Ah[2][8][64][8];
    __shared__ ushort Al[2][8][64][8];
    __shared__ ushort Bh2[2][8][64][8];
    __shared__ ushort Bl2[2][8][64][8];
    __shared__ float Gs[1024];
    __shared__ float Bt[1024];

    const int tid = threadIdx.x;
    const int l = tid & 63;
    const int wave = tid >> 6;
    const int wy = wave >> 1, wx = wave & 1;
    const int rowBase = blockIdx.y * 128;
    const int nBase   = blockIdx.x * 128;

    *(float4*)&Gs[tid * 4] = *(const float4*)(gamma + tid * 4);
    *(float4*)&Bt[tid * 4] = *(const float4*)(beta + tid * 4);

    f32x4 acc[4][4];
#pragma unroll
    for (int mt = 0; mt < 4; ++mt)
#pragma unroll
        for (int nt = 0; nt < 4; ++nt) acc[mt][nt] = (f32x4)0.f;

    const int srow = tid >> 3, skq = tid & 7;
    const int sn = tid & 127, sdq = tid >> 7;
    int aidx[4];
    float amu[4], ars[4];
#pragma unroll
    for (int i = 0; i < 4; ++i) {
        int grow = rowBase + srow + i * 32;
        aidx[i] = idxArr[grow];
        amu[i] = MU[grow];
        ars[i] = RS[grow];
    }

    __syncthreads();

    float4 pz[4], pxv[4], pbv[4];
#pragma unroll
    for (int i = 0; i < 4; ++i) {
        int col = skq * 4;
        pz[i]  = *(const float4*)(W + (size_t)aidx[i] * D + col);
        pxv[i] = *(const float4*)(X + (size_t)(rowBase + srow + i * 32) * D + col);
    }
#pragma unroll
    for (int i = 0; i < 4; ++i) {
        const float* bp = B + (size_t)((sdq + i * 2) * 4) * D + nBase + sn;
        pbv[i] = {bp[0], bp[D], bp[2 * D], bp[3 * D]};
    }

    for (int kc = 0; kc < 32; ++kc) {
        const int bsel = kc & 1;
#pragma unroll
        for (int i = 0; i < 4; ++i) {
            int row = srow + i * 32;
            int col = kc * 32 + skq * 4;
            float4 z = pz[i], xv = pxv[i];
            float4 g  = *(const float4*)&Gs[col];
            float4 bb = *(const float4*)&Bt[col];
            float4 a;
            a.x = (((z.x - xv.x) + xv.x) - amu[i]) * ars[i] * g.x + bb.x;
            a.y = (((z.y - xv.y) + xv.y) - amu[i]) * ars[i] * g.y + bb.y;
            a.z = (((z.z - xv.z) + xv.z) - amu[i]) * ars[i] * g.z + bb.z;
            a.w = (((z.w - xv.w) + xv.w) - amu[i]) * ars[i] * g.w + bb.w;
            uint2 hw, lw;
            split4(a, hw, lw);
            int tile = row >> 4;
            int lf = (row & 15) | ((skq >> 1) << 4);
            int j0 = (skq & 1) * 4;
            *(uint2*)&Ah[bsel][tile][lf][j0] = hw;
            *(uint2*)&Al[bsel][tile][lf][j0] = lw;
        }
#pragma unroll
        for (int i = 0; i < 4; ++i) {
            int dq = sdq + i * 2;
            uint2 hw, lw;
            split4(pbv[i], hw, lw);
            int tile = sn >> 4;
            int lf = (sn & 15) | ((dq >> 1) << 4);
            int j0 = (dq & 1) * 4;
            *(uint2*)&Bh2[bsel][tile][lf][j0] = hw;
            *(uint2*)&Bl2[bsel][tile][lf][j0] = lw;
        }
        __syncthreads();
        float4 pzn[4], pxvn[4], pbvn[4];
        if (kc < 31) {
#pragma unroll
            for (int i = 0; i < 4; ++i) {
                int col = (kc + 1) * 32 + skq * 4;
                pzn[i]  = *(const float4*)(W + (size_t)aidx[i] * D + col);
                pxvn[i] = *(const float4*)(X + (size_t)(rowBase + srow + i * 32) * D + col);
            }
#pragma unroll
            for (int i = 0; i < 4; ++i) {
                const float* bp = B + (size_t)((kc + 1) * 32 + (sdq + i * 2) * 4) * D + nBase + sn;
                pbvn[i] = {bp[0], bp[D], bp[2 * D], bp[3 * D]};
            }
        }
        bf16x8 fah[4], fal[4];
#pragma unroll
        for (int mt = 0; mt < 4; ++mt) {
            fah[mt] = *(const bf16x8*)&Ah[bsel][wy * 4 + mt][l][0];
            fal[mt] = *(const bf16x8*)&Al[bsel][wy * 4 + mt][l][0];
        }
#pragma unroll
        for (int nt = 0; nt < 4; ++nt) {
            bf16x8 bh = *(const bf16x8*)&Bh2[bsel][wx * 4 + nt][l][0];
            bf16x8 bl = *(const bf16x8*)&Bl2[bsel][wx * 4 + nt][l][0];
#pragma unroll
            for (int mt = 0; mt < 4; ++mt) {
                acc[mt][nt] = __builtin_amdgcn_mfma_f32_16x16x32_bf16(fah[mt], bh, acc[mt][nt], 0, 0, 0);
                acc[mt][nt] = __builtin_amdgcn_mfma_f32_16x16x32_bf16(fah[mt], bl, acc[mt][nt], 0, 0, 0);
                acc[mt][nt] = __builtin_amdgcn_mfma_f32_16x16x32_bf16(fal[mt], bh, acc[mt][nt], 0, 0, 0);
            }
        }
        if (kc < 31) {
#pragma unroll
            for (int i = 0; i < 4; ++i) {
                pz[i] = pzn[i]; pxv[i] = pxvn[i]; pbv[i] = pbvn[i];
            }
        }
    }

    const int q = l >> 4, c = l & 15;
#pragma unroll
    for (int mt = 0; mt < 4; ++mt)
#pragma unroll
        for (int nt = 0; nt < 4; ++nt)
#pragma unroll
            for (int r = 0; r < 4; ++r) {
                int grow = rowBase + wy * 64 + mt * 16 + q * 4 + r;
                int gcol = nBase + wx * 64 + nt * 16 + c;
                Out[(size_t)grow * D + gcol] = acc[mt][nt][r];
            }
}

extern "C" void kernel_launch(void* const* d_in, const int* in_sizes, int n_in,
                              void* d_out, int out_size, void* d_ws, size_t ws_size,
                              hipStream_t stream) {
    const float* X     = (const float*)d_in[0];
    const float* W     = (const float*)d_in[1];
    const float* gamma = (const float*)d_in[2];
    const float* beta  = (const float*)d_in[3];
    const float* OW    = (const float*)d_in[4];

    float* out    = (float*)d_out;
    float* outIdx = out;
    float* outSim = out + NROWS;
    float* outO   = out + 2 * NROWS;

    // scratch carved from the 32 MB outO region (all consumed before gemm2 writes it):
    //   Xq8 8 MB | Wq8 16 MB | candCol u16 4 MB | count 32 KB | SA 32 KB | SB 64 KB | RKS 64 KB
    unsigned char* Xq8 = (unsigned char*)outO;
    unsigned char* Wq8 = Xq8 + (size_t)NROWS * D;
    ushort* candCol = (ushort*)(Wq8 + (size_t)V * D);
    unsigned int* count = (unsigned int*)(candCol + (size_t)NROWS * NCAND);
    float* SA  = (float*)(count + NROWS);
    float* SB  = SA + NROWS;
    float* RKS = SB + V;

    // workspace — ~320 KB
    unsigned long long* packed = (unsigned long long*)d_ws;
    float* RK     = (float*)(packed + NROWS);
    float* RQ     = RK + V;
    float* MU     = RQ + NROWS;
    float* RS     = MU + NROWS;
    int*   idxArr = (int*)(RS + NROWS);

    hipLaunchKernelGGL(prep_kernel, dim3((V + NROWS) / 4), dim3(256), 0, stream,
                       W, X, RK, RQ, SA, SB, RKS, packed, count);
    hipLaunchKernelGGL(pack_i8_kernel, dim3(NROWS), dim3(256), 0, stream, X, SA, Xq8);
    hipLaunchKernelGGL(pack_i8_kernel, dim3(V), dim3(256), 0, stream, W, SB, Wq8);

    // 2 column chunks of 8192 keep the cross-chunk running-max head start (bounds rescore work)
    for (int ch = 0; ch < 2; ++ch) {
        int colBase = ch * 8192;
        int perX = (8192 / 128) / 8;   // 8 col-tiles per XCD
        hipLaunchKernelGGL(gemm1_kernel, dim3((NROWS / 128) * (8192 / 128)), dim3(256), 0, stream,
                           Xq8, Wq8, SA, RKS, packed, count, candCol, colBase, perX);
    }

    hipLaunchKernelGGL(rescore_kernel, dim3(NROWS / 4), dim3(256), 0, stream,
                       X, W, RK, RQ, count, candCol, outIdx, outSim, idxArr, MU, RS);
    hipLaunchKernelGGL(gemm2_kernel, dim3(D / 128, NROWS / 128), dim3(256), 0, stream,
                       X, W, idxArr, MU, RS, gamma, beta, OW, outO);
}

// Round 8
// 499.537 us; speedup vs baseline: 1.2981x; 1.0552x over previous
//
#include <hip/hip_runtime.h>
#include <math.h>

#define D 1024
#define V 16384
#define NROWS 8192
#define NCAND 256
#define DELTA 0.15f

typedef __bf16 bf16_t;
typedef bf16_t bf16x8 __attribute__((ext_vector_type(8)));
typedef float f32x4 __attribute__((ext_vector_type(4)));
typedef int i32x4 __attribute__((ext_vector_type(4)));

__device__ __forceinline__ unsigned int sortable_key(float v) {
    unsigned int b = __float_as_uint(v);
    return (b & 0x80000000u) ? ~b : (b | 0x80000000u);
}
__device__ __forceinline__ float unkey(unsigned int key) {
    unsigned int b = (key & 0x80000000u) ? (key & 0x7FFFFFFFu) : ~key;
    return __uint_as_float(b);
}
__device__ __forceinline__ void split4(float4 v, uint2& hw, uint2& lw) {
    unsigned int u0 = __float_as_uint(v.x), u1 = __float_as_uint(v.y);
    unsigned int u2 = __float_as_uint(v.z), u3 = __float_as_uint(v.w);
    float l0 = v.x - __uint_as_float(u0 & 0xFFFF0000u);
    float l1 = v.y - __uint_as_float(u1 & 0xFFFF0000u);
    float l2 = v.z - __uint_as_float(u2 & 0xFFFF0000u);
    float l3 = v.w - __uint_as_float(u3 & 0xFFFF0000u);
    hw.x = (u0 >> 16) | (u1 & 0xFFFF0000u);
    hw.y = (u2 >> 16) | (u3 & 0xFFFF0000u);
    lw.x = (__float_as_uint(l0) >> 16) | (__float_as_uint(l1) & 0xFFFF0000u);
    lw.y = (__float_as_uint(l2) >> 16) | (__float_as_uint(l3) & 0xFFFF0000u);
}

// async 16B global->LDS copy (per-lane global addr; LDS dest = wave-uniform base + lane*16)
__device__ __forceinline__ void gload16(const unsigned char* g, unsigned char* s) {
    __builtin_amdgcn_global_load_lds((const __attribute__((address_space(1))) void*)g,
                                     (__attribute__((address_space(3))) void*)s,
                                     16, 0, 0);
}

// ---------------- merged: row L2-norms + row amax (for i8 scales) of W and X ----------------
__global__ __launch_bounds__(256) void prep_kernel(const float* __restrict__ W,
                                                   const float* __restrict__ X,
                                                   float* __restrict__ RK,
                                                   float* __restrict__ RQ,
                                                   float* __restrict__ SA,
                                                   float* __restrict__ SB,
                                                   float* __restrict__ RKS,
                                                   unsigned int* __restrict__ packed,
                                                   unsigned int* __restrict__ count) {
    int tid = threadIdx.x;
    int row = blockIdx.x * 4 + (tid >> 6);
    int lane = tid & 63;
    const float* src = (row < V) ? (W + (size_t)row * D) : (X + (size_t)(row - V) * D);
    const float4* p = (const float4*)src;
    float ss = 0.f, am = 0.f;
#pragma unroll
    for (int i = 0; i < 4; ++i) {
        float4 v = p[lane + 64 * i];
        ss += v.x * v.x + v.y * v.y + v.z * v.z + v.w * v.w;
        am = fmaxf(am, fmaxf(fmaxf(fabsf(v.x), fabsf(v.y)), fmaxf(fabsf(v.z), fabsf(v.w))));
    }
#pragma unroll
    for (int m = 32; m >= 1; m >>= 1) {
        ss += __shfl_xor(ss, m, 64);
        am = fmaxf(am, __shfl_xor(am, m, 64));
    }
    if (lane == 0) {
        float rk = rsqrtf(fmaxf(ss, 1e-12f));
        float s = am * (1.f / 127.f);
        if (row < V) {
            RK[row] = rk;
            SB[row] = s;
            RKS[row] = rk * s;
        } else {
            RQ[row - V] = rk;
            SA[row - V] = s;
            packed[row - V] = 0u;
            count[row - V] = 0u;
        }
    }
}

// ---------------- quantize rows into MFMA-fragment-packed i8 (16x16x64 layout) ----------------
// element (row, k): unit = (row>>4)*16 + (k>>6); lane = (row&15) | (((k&63)>>4)<<4); byte j = k&15
// unit is 1024 bytes = 64 lanes x 16 B (linear per-lane 16B fragments).
__global__ __launch_bounds__(256) void pack_i8_kernel(const float* __restrict__ src,
                                                      const float* __restrict__ S,
                                                      unsigned char* __restrict__ dst) {
    int tid = threadIdx.x;
    int row = blockIdx.x;
    int k0 = tid * 4;
    float4 v = *((const float4*)(src + (size_t)row * D) + tid);
    float s = S[row];
    float inv = (s > 0.f) ? (1.f / s) : 0.f;
    int q0 = (int)rintf(v.x * inv), q1 = (int)rintf(v.y * inv);
    int q2 = (int)rintf(v.z * inv), q3 = (int)rintf(v.w * inv);
    q0 = q0 > 127 ? 127 : (q0 < -127 ? -127 : q0);
    q1 = q1 > 127 ? 127 : (q1 < -127 ? -127 : q1);
    q2 = q2 > 127 ? 127 : (q2 < -127 ? -127 : q2);
    q3 = q3 > 127 ? 127 : (q3 < -127 ? -127 : q3);
    unsigned int word = (unsigned int)(q0 & 0xFF) | ((unsigned int)(q1 & 0xFF) << 8) |
                        ((unsigned int)(q2 & 0xFF) << 16) | ((unsigned int)(q3 & 0xFF) << 24);
    int kc = k0 >> 6, kk = k0 & 63;
    int lane = (row & 15) | ((kk >> 4) << 4);
    int j0 = kk & 15;
    size_t idx = ((size_t)(row >> 4) * 16 + kc) * 1024 + lane * 16 + j0;
    *(unsigned int*)(dst + idx) = word;
}

// ---------------- approx sim GEMM (i8): 128x256 block, 64x128/wave, BK=128, 48KB LDS ----------------
// m97-structure with a 2x fatter wave tile (m92->m93 lever): per kc-pair each wave stages 12x1KB
// units, one sync-pair, then 2 register-sequential sub-blocks {12x ds_read_b128, 32x
// mfma_i32_16x16x64_i8}. LDS reads drop to 375 B/MFMA (vs 512 at 64x64/wave). acc = 4x8 i32x4
// (128 VGPR); launch_bounds(256,2) -> 2 blocks/CU resident, co-resident block covers drains.
// Epilogue simplified to f32 max + u32 sortable atomicMax (argmax col recovered by exact rescore).
__global__ __launch_bounds__(256, 2) void gemm1_kernel(const unsigned char* __restrict__ Xq,
                                                       const unsigned char* __restrict__ Wq,
                                                       const float* __restrict__ SA,
                                                       const float* __restrict__ RKS,
                                                       unsigned int* __restrict__ packed,
                                                       unsigned int* __restrict__ count,
                                                       ushort* __restrict__ candCol,
                                                       int colBase, int perX) {
    __shared__ __align__(16) unsigned char lds[49152];
    __shared__ float red[128][2];
    __shared__ float gthr[128];

    const int tid = threadIdx.x;
    const int l = tid & 63;
    const int w = tid >> 6;                 // 0..3
    const int wy = w >> 1, wx = w & 1;      // wave tile: 64 rows x 128 cols
    const int lin = blockIdx.x;
    const int x = lin & 7;
    const int j = lin >> 3;
    const int rt = j / perX;
    const int ctl = x * perX + (j - rt * perX);
    const int rowBase = rt * 128;
    const int cwLocal = ctl * 256;

    i32x4 acc[4][8];
#pragma unroll
    for (int mt = 0; mt < 4; ++mt)
#pragma unroll
        for (int nt = 0; nt < 8; ++nt) acc[mt][nt] = (i32x4)0;

    // unit bases: A row-groups rt*8..+7 (8 groups); B col-groups colBase/16 + ctl*16..+15 (16 groups)
    const unsigned char* As = Xq + ((size_t)(rt * 8) * 16) * 1024;
    const unsigned char* Bs = Wq + ((size_t)((colBase >> 4) + ctl * 16) * 16) * 1024;

    // LDS: A unit (u 0-7, jj) at (u*2+jj)*1024 (16KB); B unit (u 0-15, jj) at 16384+(u*2+jj)*1024 (32KB)
#pragma unroll 1
    for (int kc = 0; kc < 16; kc += 2) {
        // stage: wave w loads A units {2w,2w+1} x {jj} and B units {4w..4w+3} x {jj} (12 gloads/wave)
#pragma unroll
        for (int i = 0; i < 2; ++i) {
            int u = 2 * w + i;
#pragma unroll
            for (int jj = 0; jj < 2; ++jj)
                gload16(As + ((size_t)(u * 16 + kc + jj)) * 1024 + l * 16,
                        lds + (u * 2 + jj) * 1024);
        }
#pragma unroll
        for (int i = 0; i < 4; ++i) {
            int u = 4 * w + i;
#pragma unroll
            for (int jj = 0; jj < 2; ++jj)
                gload16(Bs + ((size_t)(u * 16 + kc + jj)) * 1024 + l * 16,
                        lds + 16384 + (u * 2 + jj) * 1024);
        }
        __syncthreads();          // drains vmcnt(0) — staged data visible
#pragma unroll
        for (int jj = 0; jj < 2; ++jj) {
            i32x4 af[4], bf[8];
#pragma unroll
            for (int mi = 0; mi < 4; ++mi)
                af[mi] = *(const i32x4*)(lds + ((wy * 4 + mi) * 2 + jj) * 1024 + l * 16);
#pragma unroll
            for (int nt = 0; nt < 8; ++nt)
                bf[nt] = *(const i32x4*)(lds + 16384 + ((wx * 8 + nt) * 2 + jj) * 1024 + l * 16);
#pragma unroll
            for (int nt = 0; nt < 8; ++nt)
#pragma unroll
                for (int mi = 0; mi < 4; ++mi)
                    acc[mi][nt] = __builtin_amdgcn_mfma_i32_16x16x64_i8(af[mi], bf[nt], acc[mi][nt], 0, 0, 0);
        }
        __syncthreads();          // all waves done reading before next overwrite
    }

    // ---- epilogue stage 1: per-row block max (value only) -> global running max (u32 key) ----
    const int q = l >> 4, c = l & 15;
    float rk_l[8];
#pragma unroll
    for (int nt = 0; nt < 8; ++nt) rk_l[nt] = RKS[colBase + cwLocal + wx * 128 + nt * 16 + c];
#pragma unroll
    for (int mt = 0; mt < 4; ++mt) {
#pragma unroll
        for (int r = 0; r < 4; ++r) {
            int lrow = wy * 64 + mt * 16 + q * 4 + r;
            float sa = SA[rowBase + lrow];
            float vmax = -1e30f;
#pragma unroll
            for (int nt = 0; nt < 8; ++nt)
                vmax = fmaxf(vmax, (float)acc[mt][nt][r] * sa * rk_l[nt]);
#pragma unroll
            for (int m = 1; m < 16; m <<= 1)
                vmax = fmaxf(vmax, __shfl_xor(vmax, m, 64));
            if (c == 0) red[lrow][wx] = vmax;
        }
    }
    __syncthreads();
    if (tid < 128) {
        float a = fmaxf(red[tid][0], red[tid][1]);
        unsigned int k = sortable_key(a);
        unsigned int old = atomicMax(packed + (rowBase + tid), k);
        unsigned int g = (old > k) ? old : k;
        gthr[tid] = unkey(g) - DELTA;
    }
    __syncthreads();
    // ---- epilogue stage 2: append candidates within DELTA of known running max ----
#pragma unroll
    for (int mt = 0; mt < 4; ++mt) {
#pragma unroll
        for (int r = 0; r < 4; ++r) {
            int lrow = wy * 64 + mt * 16 + q * 4 + r;
            float thr = gthr[lrow];
            int grow = rowBase + lrow;
            float sa = SA[grow];
#pragma unroll
            for (int nt = 0; nt < 8; ++nt) {
                float v = (float)acc[mt][nt][r] * sa * rk_l[nt];
                if (v >= thr) {
                    unsigned int slot = atomicAdd(count + grow, 1u);
                    if (slot < NCAND) {
                        int col = colBase + cwLocal + wx * 128 + nt * 16 + c;
                        candCol[(size_t)grow * NCAND + slot] = (ushort)col;
                    }
                }
            }
        }
    }
}

// ---------------- exact fp32 rescore + LN stats (merged) ----------------
__global__ __launch_bounds__(256) void rescore_kernel(const float* __restrict__ X,
                                                      const float* __restrict__ W,
                                                      const float* __restrict__ RK,
                                                      const float* __restrict__ RQ,
                                                      const unsigned int* __restrict__ count,
                                                      const ushort* __restrict__ candCol,
                                                      float* __restrict__ outIdx,
                                                      float* __restrict__ outSim,
                                                      int* __restrict__ idxArr,
                                                      float* __restrict__ MU,
                                                      float* __restrict__ RS) {
    int wave = threadIdx.x >> 6, l = threadIdx.x & 63;
    int row = blockIdx.x * 4 + wave;
    unsigned int n = count[row];
    if (n > NCAND) n = NCAND;
    const float4* X4 = (const float4*)X + (size_t)row * 256;
    unsigned long long best = 0;
    for (unsigned int i = 0; i < n; ++i) {
        int col = (int)candCol[(size_t)row * NCAND + i];
        const float4* W4 = (const float4*)W + (size_t)col * 256;
        float s = 0.f;
#pragma unroll
        for (int jj = 0; jj < 4; ++jj) {
            float4 a = X4[jj * 64 + l];
            float4 b = W4[jj * 64 + l];
            s += a.x * b.x + a.y * b.y + a.z * b.z + a.w * b.w;
        }
#pragma unroll
        for (int m = 32; m >= 1; m >>= 1) s += __shfl_xor(s, m, 64);
        float v = s * RK[col];
        unsigned long long pk = ((unsigned long long)sortable_key(v) << 32) |
                                (unsigned long long)(~(unsigned int)col);
        if (pk > best) best = pk;
    }
    int idx = (int)(~(unsigned int)(best & 0xFFFFFFFFull)) & 0xFFFF;
    const float4* Z4 = (const float4*)W + (size_t)idx * 256;
    float s = 0.f, s2 = 0.f;
#pragma unroll
    for (int jj = 0; jj < 4; ++jj) {
        float4 a = X4[jj * 64 + l];
        float4 z = Z4[jj * 64 + l];
        float4 e;
        e.x = (z.x - a.x) + a.x;
        e.y = (z.y - a.y) + a.y;
        e.z = (z.z - a.z) + a.z;
        e.w = (z.w - a.w) + a.w;
        s  += e.x + e.y + e.z + e.w;
        s2 += e.x * e.x + e.y * e.y + e.z * e.z + e.w * e.w;
    }
#pragma unroll
    for (int m = 32; m >= 1; m >>= 1) {
        s  += __shfl_xor(s, m, 64);
        s2 += __shfl_xor(s2, m, 64);
    }
    if (l == 0) {
        outIdx[row] = (float)idx;
        outSim[row] = unkey((unsigned int)(best >> 32)) * RQ[row];
        idxArr[row] = idx;
        float mean = s * (1.f / D);
        float var  = s2 * (1.f / D) - mean * mean;
        MU[row] = mean;
        RS[row] = rsqrtf(var + 1e-6f);
    }
}

// ---------------- projection GEMM: bf16 3-pass MFMA, LN fused into A staging ----------------
__global__ __launch_bounds__(256, 2) void gemm2_kernel(const float* __restrict__ X,
                                                       const float* __restrict__ W,
                                                       const int* __restrict__ idxArr,
                                                       const float* __restrict__ MU,
                                                       const float* __restrict__ RS,
                                                       const float* __restrict__ gamma,
                                                       const float* __restrict__ beta,
                                                       const float* __restrict__ B,
                                                       float* __restrict__ Out) {
    __shared__ ushort Ah[2][8][64][8];
    __shared__ ushort Al[2][8][64][8];
    __shared__ ushort Bh2[2][8][64][8];
    __shared__ ushort Bl2[2][8][64][8];
    __shared__ float Gs[1024];
    __shared__ float Bt[1024];

    const int tid = threadIdx.x;
    const int l = tid & 63;
    const int wave = tid >> 6;
    const int wy = wave >> 1, wx = wave & 1;
    const int rowBase = blockIdx.y * 128;
    const int nBase   = blockIdx.x * 128;

    *(float4*)&Gs[tid * 4] = *(const float4*)(gamma + tid * 4);
    *(float4*)&Bt[tid * 4] = *(const float4*)(beta + tid * 4);

    f32x4 acc[4][4];
#pragma unroll
    for (int mt = 0; mt < 4; ++mt)
#pragma unroll
        for (int nt = 0; nt < 4; ++nt) acc[mt][nt] = (f32x4)0.f;

    const int srow = tid >> 3, skq = tid & 7;
    const int sn = tid & 127, sdq = tid >> 7;
    int aidx[4];
    float amu[4], ars[4];
#pragma unroll
    for (int i = 0; i < 4; ++i) {
        int grow = rowBase + srow + i * 32;
        aidx[i] = idxArr[grow];
        amu[i] = MU[grow];
        ars[i] = RS[grow];
    }

    __syncthreads();

    float4 pz[4], pxv[4], pbv[4];
#pragma unroll
    for (int i = 0; i < 4; ++i) {
        int col = skq * 4;
        pz[i]  = *(const float4*)(W + (size_t)aidx[i] * D + col);
        pxv[i] = *(const float4*)(X + (size_t)(rowBase + srow + i * 32) * D + col);
    }
#pragma unroll
    for (int i = 0; i < 4; ++i) {
        const float* bp = B + (size_t)((sdq + i * 2) * 4) * D + nBase + sn;
        pbv[i] = {bp[0], bp[D], bp[2 * D], bp[3 * D]};
    }

    for (int kc = 0; kc < 32; ++kc) {
        const int bsel = kc & 1;
#pragma unroll
        for (int i = 0; i < 4; ++i) {
            int row = srow + i * 32;
            int col = kc * 32 + skq * 4;
            float4 z = pz[i], xv = pxv[i];
            float4 g  = *(const float4*)&Gs[col];
            float4 bb = *(const float4*)&Bt[col];
            float4 a;
            a.x = (((z.x - xv.x) + xv.x) - amu[i]) * ars[i] * g.x + bb.x;
            a.y = (((z.y - xv.y) + xv.y) - amu[i]) * ars[i] * g.y + bb.y;
            a.z = (((z.z - xv.z) + xv.z) - amu[i]) * ars[i] * g.z + bb.z;
            a.w = (((z.w - xv.w) + xv.w) - amu[i]) * ars[i] * g.w + bb.w;
            uint2 hw, lw;
            split4(a, hw, lw);
            int tile = row >> 4;
            int lf = (row & 15) | ((skq >> 1) << 4);
            int j0 = (skq & 1) * 4;
            *(uint2*)&Ah[bsel][tile][lf][j0] = hw;
            *(uint2*)&Al[bsel][tile][lf][j0] = lw;
        }
#pragma unroll
        for (int i = 0; i < 4; ++i) {
            int dq = sdq + i * 2;
            uint2 hw, lw;
            split4(pbv[i], hw, lw);
            int tile = sn >> 4;
            int lf = (sn & 15) | ((dq >> 1) << 4);
            int j0 = (dq & 1) * 4;
            *(uint2*)&Bh2[bsel][tile][lf][j0] = hw;
            *(uint2*)&Bl2[bsel][tile][lf][j0] = lw;
        }
        __syncthreads();
        float4 pzn[4], pxvn[4], pbvn[4];
        if (kc < 31) {
#pragma unroll
            for (int i = 0; i < 4; ++i) {
                int col = (kc + 1) * 32 + skq * 4;
                pzn[i]  = *(const float4*)(W + (size_t)aidx[i] * D + col);
                pxvn[i] = *(const float4*)(X + (size_t)(rowBase + srow + i * 32) * D + col);
            }
#pragma unroll
            for (int i = 0; i < 4; ++i) {
                const float* bp = B + (size_t)((kc + 1) * 32 + (sdq + i * 2) * 4) * D + nBase + sn;
                pbvn[i] = {bp[0], bp[D], bp[2 * D], bp[3 * D]};
            }
        }
        bf16x8 fah[4], fal[4];
#pragma unroll
        for (int mt = 0; mt < 4; ++mt) {
            fah[mt] = *(const bf16x8*)&Ah[bsel][wy * 4 + mt][l][0];
            fal[mt] = *(const bf16x8*)&Al[bsel][wy * 4 + mt][l][0];
        }
#pragma unroll
        for (int nt = 0; nt < 4; ++nt) {
            bf16x8 bh = *(const bf16x8*)&Bh2[bsel][wx * 4 + nt][l][0];
            bf16x8 bl = *(const bf16x8*)&Bl2[bsel][wx * 4 + nt][l][0];
#pragma unroll
            for (int mt = 0; mt < 4; ++mt) {
                acc[mt][nt] = __builtin_amdgcn_mfma_f32_16x16x32_bf16(fah[mt], bh, acc[mt][nt], 0, 0, 0);
                acc[mt][nt] = __builtin_amdgcn_mfma_f32_16x16x32_bf16(fah[mt], bl, acc[mt][nt], 0, 0, 0);
                acc[mt][nt] = __builtin_amdgcn_mfma_f32_16x16x32_bf16(fal[mt], bh, acc[mt][nt], 0, 0, 0);
            }
        }
        if (kc < 31) {
#pragma unroll
            for (int i = 0; i < 4; ++i) {
                pz[i] = pzn[i]; pxv[i] = pxvn[i]; pbv[i] = pbvn[i];
            }
        }
    }

    const int q = l >> 4, c = l & 15;
#pragma unroll
    for (int mt = 0; mt < 4; ++mt)
#pragma unroll
        for (int nt = 0; nt < 4; ++nt)
#pragma unroll
            for (int r = 0; r < 4; ++r) {
                int grow = rowBase + wy * 64 + mt * 16 + q * 4 + r;
                int gcol = nBase + wx * 64 + nt * 16 + c;
                Out[(size_t)grow * D + gcol] = acc[mt][nt][r];
            }
}

extern "C" void kernel_launch(void* const* d_in, const int* in_sizes, int n_in,
                              void* d_out, int out_size, void* d_ws, size_t ws_size,
                              hipStream_t stream) {
    const float* X     = (const float*)d_in[0];
    const float* W     = (const float*)d_in[1];
    const float* gamma = (const float*)d_in[2];
    const float* beta  = (const float*)d_in[3];
    const float* OW    = (const float*)d_in[4];

    float* out    = (float*)d_out;
    float* outIdx = out;
    float* outSim = out + NROWS;
    float* outO   = out + 2 * NROWS;

    // scratch carved from the 32 MB outO region (all consumed before gemm2 writes it):
    //   Xq8 8 MB | Wq8 16 MB | candCol u16 4 MB | count 32 KB | SA 32 KB | SB 64 KB | RKS 64 KB
    unsigned char* Xq8 = (unsigned char*)outO;
    unsigned char* Wq8 = Xq8 + (size_t)NROWS * D;
    ushort* candCol = (ushort*)(Wq8 + (size_t)V * D);
    unsigned int* count = (unsigned int*)(candCol + (size_t)NROWS * NCAND);
    float* SA  = (float*)(count + NROWS);
    float* SB  = SA + NROWS;
    float* RKS = SB + V;

    // workspace — ~320 KB
    unsigned int* packed = (unsigned int*)d_ws;
    float* RK     = (float*)(packed + NROWS);
    float* RQ     = RK + V;
    float* MU     = RQ + NROWS;
    float* RS     = MU + NROWS;
    int*   idxArr = (int*)(RS + NROWS);

    hipLaunchKernelGGL(prep_kernel, dim3((V + NROWS) / 4), dim3(256), 0, stream,
                       W, X, RK, RQ, SA, SB, RKS, packed, count);
    hipLaunchKernelGGL(pack_i8_kernel, dim3(NROWS), dim3(256), 0, stream, X, SA, Xq8);
    hipLaunchKernelGGL(pack_i8_kernel, dim3(V), dim3(256), 0, stream, W, SB, Wq8);

    // 2 column chunks of 8192 keep the cross-chunk running-max head start (bounds rescore work)
    for (int ch = 0; ch < 2; ++ch) {
        int colBase = ch * 8192;
        int perX = (8192 / 256) / 8;   // 4 col-tiles (256-wide) per XCD
        hipLaunchKernelGGL(gemm1_kernel, dim3((NROWS / 128) * (8192 / 256)), dim3(256), 0, stream,
                           Xq8, Wq8, SA, RKS, packed, count, candCol, colBase, perX);
    }

    hipLaunchKernelGGL(rescore_kernel, dim3(NROWS / 4), dim3(256), 0, stream,
                       X, W, RK, RQ, count, candCol, outIdx, outSim, idxArr, MU, RS);
    hipLaunchKernelGGL(gemm2_kernel, dim3(D / 128, NROWS / 128), dim3(256), 0, stream,
                       X, W, idxArr, MU, RS, gamma, beta, OW, outO);
}

// Round 9
// 491.187 us; speedup vs baseline: 1.3202x; 1.0170x over previous
//
#include <hip/hip_runtime.h>
#include <math.h>

#define D 1024
#define V 16384
#define NROWS 8192
#define NCAND 256
#define DELTA 0.15f

typedef __bf16 bf16_t;
typedef bf16_t bf16x8 __attribute__((ext_vector_type(8)));
typedef float f32x4 __attribute__((ext_vector_type(4)));
typedef int i32x4 __attribute__((ext_vector_type(4)));

__device__ __forceinline__ unsigned int sortable_key(float v) {
    unsigned int b = __float_as_uint(v);
    return (b & 0x80000000u) ? ~b : (b | 0x80000000u);
}
__device__ __forceinline__ float unkey(unsigned int key) {
    unsigned int b = (key & 0x80000000u) ? (key & 0x7FFFFFFFu) : ~key;
    return __uint_as_float(b);
}
__device__ __forceinline__ void split4(float4 v, uint2& hw, uint2& lw) {
    unsigned int u0 = __float_as_uint(v.x), u1 = __float_as_uint(v.y);
    unsigned int u2 = __float_as_uint(v.z), u3 = __float_as_uint(v.w);
    float l0 = v.x - __uint_as_float(u0 & 0xFFFF0000u);
    float l1 = v.y - __uint_as_float(u1 & 0xFFFF0000u);
    float l2 = v.z - __uint_as_float(u2 & 0xFFFF0000u);
    float l3 = v.w - __uint_as_float(u3 & 0xFFFF0000u);
    hw.x = (u0 >> 16) | (u1 & 0xFFFF0000u);
    hw.y = (u2 >> 16) | (u3 & 0xFFFF0000u);
    lw.x = (__float_as_uint(l0) >> 16) | (__float_as_uint(l1) & 0xFFFF0000u);
    lw.y = (__float_as_uint(l2) >> 16) | (__float_as_uint(l3) & 0xFFFF0000u);
}

// async 16B global->LDS copy (per-lane global addr; LDS dest = wave-uniform base + lane*16)
__device__ __forceinline__ void gload16(const unsigned char* g, unsigned char* s) {
    __builtin_amdgcn_global_load_lds((const __attribute__((address_space(1))) void*)g,
                                     (__attribute__((address_space(3))) void*)s,
                                     16, 0, 0);
}

// ---------------- fused: row L2-norm + amax + i8 quantize + fragment-pack (one read of src) ----------------
// 256 threads/row; thread t handles elems [4t,4t+4). Fragment layout (16x16x64 i8 MFMA):
// unit = (row>>4)*16 + (k>>6) [1024B]; lane = (row&15) | (((k&63)>>4)<<4); byte j = k&15.
// W mode (isX=0): writes RK[row], RKS[row]=rk*s.  X mode (isX=1): RQ[row], SA[row]=s, zeroes packed/count.
__global__ __launch_bounds__(256) void packq_kernel(const float* __restrict__ src,
                                                    unsigned char* __restrict__ dst,
                                                    float* __restrict__ oRK,
                                                    float* __restrict__ oS,
                                                    unsigned int* __restrict__ packed,
                                                    unsigned int* __restrict__ count,
                                                    int isX) {
    __shared__ float rss[4], ram[4];
    __shared__ float binv;
    int tid = threadIdx.x;
    int row = blockIdx.x;
    float4 v = *((const float4*)(src + (size_t)row * D) + tid);
    float ss = v.x * v.x + v.y * v.y + v.z * v.z + v.w * v.w;
    float am = fmaxf(fmaxf(fabsf(v.x), fabsf(v.y)), fmaxf(fabsf(v.z), fabsf(v.w)));
#pragma unroll
    for (int m = 32; m >= 1; m >>= 1) {
        ss += __shfl_xor(ss, m, 64);
        am = fmaxf(am, __shfl_xor(am, m, 64));
    }
    int wv = tid >> 6, ln = tid & 63;
    if (ln == 0) { rss[wv] = ss; ram[wv] = am; }
    __syncthreads();
    if (tid == 0) {
        float S = (rss[0] + rss[1]) + (rss[2] + rss[3]);
        float A = fmaxf(fmaxf(ram[0], ram[1]), fmaxf(ram[2], ram[3]));
        float rk = rsqrtf(fmaxf(S, 1e-12f));
        float s = A * (1.f / 127.f);
        if (isX) {
            oRK[row] = rk;        // RQ
            oS[row]  = s;         // SA
            packed[row] = 0u;
            count[row]  = 0u;
        } else {
            oRK[row] = rk;        // RK
            oS[row]  = rk * s;    // RKS
        }
        binv = (s > 0.f) ? (1.f / s) : 0.f;
    }
    __syncthreads();
    float inv = binv;
    int q0 = (int)rintf(v.x * inv), q1 = (int)rintf(v.y * inv);
    int q2 = (int)rintf(v.z * inv), q3 = (int)rintf(v.w * inv);
    q0 = q0 > 127 ? 127 : (q0 < -127 ? -127 : q0);
    q1 = q1 > 127 ? 127 : (q1 < -127 ? -127 : q1);
    q2 = q2 > 127 ? 127 : (q2 < -127 ? -127 : q2);
    q3 = q3 > 127 ? 127 : (q3 < -127 ? -127 : q3);
    unsigned int word = (unsigned int)(q0 & 0xFF) | ((unsigned int)(q1 & 0xFF) << 8) |
                        ((unsigned int)(q2 & 0xFF) << 16) | ((unsigned int)(q3 & 0xFF) << 24);
    int k0 = tid * 4;
    int kc = k0 >> 6, kk = k0 & 63;
    int lane = (row & 15) | ((kk >> 4) << 4);
    int j0 = kk & 15;
    size_t idx = ((size_t)(row >> 4) * 16 + kc) * 1024 + lane * 16 + j0;
    *(unsigned int*)(dst + idx) = word;
}

// ---------------- approx sim GEMM (i8): stage-first double-buffered 2-phase (T3-minimum) ----------------
// 128x256 block tile, 64x128/wave (4 waves), BK=64, LDS = 2 x 24KB dbuf. Per K-step:
//   STAGE(kc+1 -> buf^1)  [6 gload_lds/wave, issued FIRST]
//   sched_barrier; 12x ds_read_b128 from buf; 32x mfma_i32_16x16x64_i8
//   __syncthreads  [drains vmcnt(0): kc+1's loads, issued ~1300cyc earlier -> delivery hidden]
// Single dispatch over all 16384 cols (64 rt x 64 ctl, XCD-swizzled). Fragment-packed layout
// keeps gload_lds dests linear and ds_reads conflict-free. Epilogue: f32 max + u32 atomicMax.
__global__ __launch_bounds__(256, 2) void gemm1_kernel(const unsigned char* __restrict__ Xq,
                                                       const unsigned char* __restrict__ Wq,
                                                       const float* __restrict__ SA,
                                                       const float* __restrict__ RKS,
                                                       unsigned int* __restrict__ packed,
                                                       unsigned int* __restrict__ count,
                                                       ushort* __restrict__ candCol) {
    __shared__ __align__(16) unsigned char lds[49152];   // 2 x (A 8KB + B 16KB)
    __shared__ float red[128][2];
    __shared__ float gthr[128];

    const int tid = threadIdx.x;
    const int l = tid & 63;
    const int w = tid >> 6;                 // 0..3
    const int wy = w >> 1, wx = w & 1;      // wave tile: 64 rows x 128 cols
    const int lin = blockIdx.x;
    const int x = lin & 7;                  // XCD
    const int j = lin >> 3;
    const int rt = j >> 3;                  // [0,64)
    const int ctl = x * 8 + (j & 7);        // [0,64) — 8 col-tiles per XCD, L2-local B slice
    const int rowBase = rt * 128;
    const int colBase = ctl * 256;

    i32x4 acc[4][8];
#pragma unroll
    for (int mt = 0; mt < 4; ++mt)
#pragma unroll
        for (int nt = 0; nt < 8; ++nt) acc[mt][nt] = (i32x4)0;

    // A row-groups rt*8..+7 (8 units/kc); B col-groups ctl*16..+15 (16 units/kc)
    const unsigned char* As = Xq + ((size_t)(rt * 8) * 16) * 1024;
    const unsigned char* Bs = Wq + ((size_t)(ctl * 16) * 16) * 1024;

    // prologue: stage kc=0 into buf0, full drain
#pragma unroll
    for (int i = 0; i < 2; ++i) {
        int u = 2 * w + i;
        gload16(As + ((size_t)(u * 16 + 0)) * 1024 + l * 16, lds + u * 1024);
    }
#pragma unroll
    for (int i = 0; i < 4; ++i) {
        int u = 4 * w + i;
        gload16(Bs + ((size_t)(u * 16 + 0)) * 1024 + l * 16, lds + 8192 + u * 1024);
    }
    __syncthreads();

#pragma unroll 1
    for (int kc = 0; kc < 16; ++kc) {
        const int cur = (kc & 1) * 24576;
        const int nxt = ((kc & 1) ^ 1) * 24576;
        if (kc + 1 < 16) {
            // stage NEXT K-step first — delivery overlaps this step's compute
#pragma unroll
            for (int i = 0; i < 2; ++i) {
                int u = 2 * w + i;
                gload16(As + ((size_t)(u * 16 + kc + 1)) * 1024 + l * 16,
                        lds + nxt + u * 1024);
            }
#pragma unroll
            for (int i = 0; i < 4; ++i) {
                int u = 4 * w + i;
                gload16(Bs + ((size_t)(u * 16 + kc + 1)) * 1024 + l * 16,
                        lds + nxt + 8192 + u * 1024);
            }
        }
        __builtin_amdgcn_sched_barrier(0);   // pin: stages issued before ds_reads
        i32x4 af[4], bf[8];
#pragma unroll
        for (int mi = 0; mi < 4; ++mi)
            af[mi] = *(const i32x4*)(lds + cur + (wy * 4 + mi) * 1024 + l * 16);
#pragma unroll
        for (int nt = 0; nt < 8; ++nt)
            bf[nt] = *(const i32x4*)(lds + cur + 8192 + (wx * 8 + nt) * 1024 + l * 16);
#pragma unroll
        for (int nt = 0; nt < 8; ++nt)
#pragma unroll
            for (int mi = 0; mi < 4; ++mi)
                acc[mi][nt] = __builtin_amdgcn_mfma_i32_16x16x64_i8(af[mi], bf[nt], acc[mi][nt], 0, 0, 0);
        __syncthreads();   // drains vmcnt(0) — kc+1 staged data visible; buffers swap safely
    }

    // ---- epilogue stage 1: per-row block max (value only) -> global running max (u32 key) ----
    const int q = l >> 4, c = l & 15;
    float rk_l[8];
#pragma unroll
    for (int nt = 0; nt < 8; ++nt) rk_l[nt] = RKS[colBase + wx * 128 + nt * 16 + c];
#pragma unroll
    for (int mt = 0; mt < 4; ++mt) {
#pragma unroll
        for (int r = 0; r < 4; ++r) {
            int lrow = wy * 64 + mt * 16 + q * 4 + r;
            float sa = SA[rowBase + lrow];
            float vmax = -1e30f;
#pragma unroll
            for (int nt = 0; nt < 8; ++nt)
                vmax = fmaxf(vmax, (float)acc[mt][nt][r] * sa * rk_l[nt]);
#pragma unroll
            for (int m = 1; m < 16; m <<= 1)
                vmax = fmaxf(vmax, __shfl_xor(vmax, m, 64));
            if (c == 0) red[lrow][wx] = vmax;
        }
    }
    __syncthreads();
    if (tid < 128) {
        float a = fmaxf(red[tid][0], red[tid][1]);
        unsigned int k = sortable_key(a);
        unsigned int old = atomicMax(packed + (rowBase + tid), k);
        unsigned int g = (old > k) ? old : k;
        gthr[tid] = unkey(g) - DELTA;
    }
    __syncthreads();
    // ---- epilogue stage 2: append candidates within DELTA of known running max ----
#pragma unroll
    for (int mt = 0; mt < 4; ++mt) {
#pragma unroll
        for (int r = 0; r < 4; ++r) {
            int lrow = wy * 64 + mt * 16 + q * 4 + r;
            float thr = gthr[lrow];
            int grow = rowBase + lrow;
            float sa = SA[grow];
#pragma unroll
            for (int nt = 0; nt < 8; ++nt) {
                float v = (float)acc[mt][nt][r] * sa * rk_l[nt];
                if (v >= thr) {
                    unsigned int slot = atomicAdd(count + grow, 1u);
                    if (slot < NCAND) {
                        int col = colBase + wx * 128 + nt * 16 + c;
                        candCol[(size_t)grow * NCAND + slot] = (ushort)col;
                    }
                }
            }
        }
    }
}

// ---------------- exact fp32 rescore + LN stats (merged) ----------------
__global__ __launch_bounds__(256) void rescore_kernel(const float* __restrict__ X,
                                                      const float* __restrict__ W,
                                                      const float* __restrict__ RK,
                                                      const float* __restrict__ RQ,
                                                      const unsigned int* __restrict__ count,
                                                      const ushort* __restrict__ candCol,
                                                      float* __restrict__ outIdx,
                                                      float* __restrict__ outSim,
                                                      int* __restrict__ idxArr,
                                                      float* __restrict__ MU,
                                                      float* __restrict__ RS) {
    int wave = threadIdx.x >> 6, l = threadIdx.x & 63;
    int row = blockIdx.x * 4 + wave;
    unsigned int n = count[row];
    if (n > NCAND) n = NCAND;
    const float4* X4 = (const float4*)X + (size_t)row * 256;
    unsigned long long best = 0;
    for (unsigned int i = 0; i < n; ++i) {
        int col = (int)candCol[(size_t)row * NCAND + i];
        const float4* W4 = (const float4*)W + (size_t)col * 256;
        float s = 0.f;
#pragma unroll
        for (int jj = 0; jj < 4; ++jj) {
            float4 a = X4[jj * 64 + l];
            float4 b = W4[jj * 64 + l];
            s += a.x * b.x + a.y * b.y + a.z * b.z + a.w * b.w;
        }
#pragma unroll
        for (int m = 32; m >= 1; m >>= 1) s += __shfl_xor(s, m, 64);
        float v = s * RK[col];
        unsigned long long pk = ((unsigned long long)sortable_key(v) << 32) |
                                (unsigned long long)(~(unsigned int)col);
        if (pk > best) best = pk;
    }
    int idx = (int)(~(unsigned int)(best & 0xFFFFFFFFull)) & 0xFFFF;
    const float4* Z4 = (const float4*)W + (size_t)idx * 256;
    float s = 0.f, s2 = 0.f;
#pragma unroll
    for (int jj = 0; jj < 4; ++jj) {
        float4 a = X4[jj * 64 + l];
        float4 z = Z4[jj * 64 + l];
        float4 e;
        e.x = (z.x - a.x) + a.x;
        e.y = (z.y - a.y) + a.y;
        e.z = (z.z - a.z) + a.z;
        e.w = (z.w - a.w) + a.w;
        s  += e.x + e.y + e.z + e.w;
        s2 += e.x * e.x + e.y * e.y + e.z * e.z + e.w * e.w;
    }
#pragma unroll
    for (int m = 32; m >= 1; m >>= 1) {
        s  += __shfl_xor(s, m, 64);
        s2 += __shfl_xor(s2, m, 64);
    }
    if (l == 0) {
        outIdx[row] = (float)idx;
        outSim[row] = unkey((unsigned int)(best >> 32)) * RQ[row];
        idxArr[row] = idx;
        float mean = s * (1.f / D);
        float var  = s2 * (1.f / D) - mean * mean;
        MU[row] = mean;
        RS[row] = rsqrtf(var + 1e-6f);
    }
}

// ---------------- projection GEMM: bf16 3-pass MFMA, LN fused into A staging ----------------
__global__ __launch_bounds__(256, 2) void gemm2_kernel(const float* __restrict__ X,
                                                       const float* __restrict__ W,
                                                       const int* __restrict__ idxArr,
                                                       const float* __restrict__ MU,
                                                       const float* __restrict__ RS,
                                                       const float* __restrict__ gamma,
                                                       const float* __restrict__ beta,
                                                       const float* __restrict__ B,
                                                       float* __restrict__ Out) {
    __shared__ ushort Ah[2][8][64][8];
    __shared__ ushort Al[2][8][64][8];
    __shared__ ushort Bh2[2][8][64][8];
    __shared__ ushort Bl2[2][8][64][8];
    __shared__ float Gs[1024];
    __shared__ float Bt[1024];

    const int tid = threadIdx.x;
    const int l = tid & 63;
    const int wave = tid >> 6;
    const int wy = wave >> 1, wx = wave & 1;
    const int rowBase = blockIdx.y * 128;
    const int nBase   = blockIdx.x * 128;

    *(float4*)&Gs[tid * 4] = *(const float4*)(gamma + tid * 4);
    *(float4*)&Bt[tid * 4] = *(const float4*)(beta + tid * 4);

    f32x4 acc[4][4];
#pragma unroll
    for (int mt = 0; mt < 4; ++mt)
#pragma unroll
        for (int nt = 0; nt < 4; ++nt) acc[mt][nt] = (f32x4)0.f;

    const int srow = tid >> 3, skq = tid & 7;
    const int sn = tid & 127, sdq = tid >> 7;
    int aidx[4];
    float amu[4], ars[4];
#pragma unroll
    for (int i = 0; i < 4; ++i) {
        int grow = rowBase + srow + i * 32;
        aidx[i] = idxArr[grow];
        amu[i] = MU[grow];
        ars[i] = RS[grow];
    }

    __syncthreads();

    float4 pz[4], pxv[4], pbv[4];
#pragma unroll
    for (int i = 0; i < 4; ++i) {
        int col = skq * 4;
        pz[i]  = *(const float4*)(W + (size_t)aidx[i] * D + col);
        pxv[i] = *(const float4*)(X + (size_t)(rowBase + srow + i * 32) * D + col);
    }
#pragma unroll
    for (int i = 0; i < 4; ++i) {
        const float* bp = B + (size_t)((sdq + i * 2) * 4) * D + nBase + sn;
        pbv[i] = {bp[0], bp[D], bp[2 * D], bp[3 * D]};
    }

    for (int kc = 0; kc < 32; ++kc) {
        const int bsel = kc & 1;
#pragma unroll
        for (int i = 0; i < 4; ++i) {
            int row = srow + i * 32;
            int col = kc * 32 + skq * 4;
            float4 z = pz[i], xv = pxv[i];
            float4 g  = *(const float4*)&Gs[col];
            float4 bb = *(const float4*)&Bt[col];
            float4 a;
            a.x = (((z.x - xv.x) + xv.x) - amu[i]) * ars[i] * g.x + bb.x;
            a.y = (((z.y - xv.y) + xv.y) - amu[i]) * ars[i] * g.y + bb.y;
            a.z = (((z.z - xv.z) + xv.z) - amu[i]) * ars[i] * g.z + bb.z;
            a.w = (((z.w - xv.w) + xv.w) - amu[i]) * ars[i] * g.w + bb.w;
            uint2 hw, lw;
            split4(a, hw, lw);
            int tile = row >> 4;
            int lf = (row & 15) | ((skq >> 1) << 4);
            int j0 = (skq & 1) * 4;
            *(uint2*)&Ah[bsel][tile][lf][j0] = hw;
            *(uint2*)&Al[bsel][tile][lf][j0] = lw;
        }
#pragma unroll
        for (int i = 0; i < 4; ++i) {
            int dq = sdq + i * 2;
            uint2 hw, lw;
            split4(pbv[i], hw, lw);
            int tile = sn >> 4;
            int lf = (sn & 15) | ((dq >> 1) << 4);
            int j0 = (dq & 1) * 4;
            *(uint2*)&Bh2[bsel][tile][lf][j0] = hw;
            *(uint2*)&Bl2[bsel][tile][lf][j0] = lw;
        }
        __syncthreads();
        float4 pzn[4], pxvn[4], pbvn[4];
        if (kc < 31) {
#pragma unroll
            for (int i = 0; i < 4; ++i) {
                int col = (kc + 1) * 32 + skq * 4;
                pzn[i]  = *(const float4*)(W + (size_t)aidx[i] * D + col);
                pxvn[i] = *(const float4*)(X + (size_t)(rowBase + srow + i * 32) * D + col);
            }
#pragma unroll
            for (int i = 0; i < 4; ++i) {
                const float* bp = B + (size_t)((kc + 1) * 32 + (sdq + i * 2) * 4) * D + nBase + sn;
                pbvn[i] = {bp[0], bp[D], bp[2 * D], bp[3 * D]};
            }
        }
        bf16x8 fah[4], fal[4];
#pragma unroll
        for (int mt = 0; mt < 4; ++mt) {
            fah[mt] = *(const bf16x8*)&Ah[bsel][wy * 4 + mt][l][0];
            fal[mt] = *(const bf16x8*)&Al[bsel][wy * 4 + mt][l][0];
        }
#pragma unroll
        for (int nt = 0; nt < 4; ++nt) {
            bf16x8 bh = *(const bf16x8*)&Bh2[bsel][wx * 4 + nt][l][0];
            bf16x8 bl = *(const bf16x8*)&Bl2[bsel][wx * 4 + nt][l][0];
#pragma unroll
            for (int mt = 0; mt < 4; ++mt) {
                acc[mt][nt] = __builtin_amdgcn_mfma_f32_16x16x32_bf16(fah[mt], bh, acc[mt][nt], 0, 0, 0);
                acc[mt][nt] = __builtin_amdgcn_mfma_f32_16x16x32_bf16(fah[mt], bl, acc[mt][nt], 0, 0, 0);
                acc[mt][nt] = __builtin_amdgcn_mfma_f32_16x16x32_bf16(fal[mt], bh, acc[mt][nt], 0, 0, 0);
            }
        }
        if (kc < 31) {
#pragma unroll
            for (int i = 0; i < 4; ++i) {
                pz[i] = pzn[i]; pxv[i] = pxvn[i]; pbv[i] = pbvn[i];
            }
        }
    }

    const int q = l >> 4, c = l & 15;
#pragma unroll
    for (int mt = 0; mt < 4; ++mt)
#pragma unroll
        for (int nt = 0; nt < 4; ++nt)
#pragma unroll
            for (int r = 0; r < 4; ++r) {
                int grow = rowBase + wy * 64 + mt * 16 + q * 4 + r;
                int gcol = nBase + wx * 64 + nt * 16 + c;
                Out[(size_t)grow * D + gcol] = acc[mt][nt][r];
            }
}

extern "C" void kernel_launch(void* const* d_in, const int* in_sizes, int n_in,
                              void* d_out, int out_size, void* d_ws, size_t ws_size,
                              hipStream_t stream) {
    const float* X     = (const float*)d_in[0];
    const float* W     = (const float*)d_in[1];
    const float* gamma = (const float*)d_in[2];
    const float* beta  = (const float*)d_in[3];
    const float* OW    = (const float*)d_in[4];

    float* out    = (float*)d_out;
    float* outIdx = out;
    float* outSim = out + NROWS;
    float* outO   = out + 2 * NROWS;

    // scratch carved from the 32 MB outO region (all consumed before gemm2 writes it):
    //   Xq8 8 MB | Wq8 16 MB | candCol u16 4 MB | count 32 KB | SA 32 KB | RKS 64 KB
    unsigned char* Xq8 = (unsigned char*)outO;
    unsigned char* Wq8 = Xq8 + (size_t)NROWS * D;
    ushort* candCol = (ushort*)(Wq8 + (size_t)V * D);
    unsigned int* count = (unsigned int*)(candCol + (size_t)NROWS * NCAND);
    float* SA  = (float*)(count + NROWS);
    float* RKS = SA + NROWS;

    // workspace — ~224 KB
    unsigned int* packed = (unsigned int*)d_ws;
    float* RK     = (float*)(packed + NROWS);
    float* RQ     = RK + V;
    float* MU     = RQ + NROWS;
    float* RS     = MU + NROWS;
    int*   idxArr = (int*)(RS + NROWS);

    // fused norm+amax+quantize+pack (single read of each tensor)
    hipLaunchKernelGGL(packq_kernel, dim3(V), dim3(256), 0, stream,
                       W, Wq8, RK, RKS, (unsigned int*)nullptr, (unsigned int*)nullptr, 0);
    hipLaunchKernelGGL(packq_kernel, dim3(NROWS), dim3(256), 0, stream,
                       X, Xq8, RQ, SA, packed, count, 1);

    // single gemm1 dispatch over all 16384 cols
    hipLaunchKernelGGL(gemm1_kernel, dim3((NROWS / 128) * (V / 256)), dim3(256), 0, stream,
                       Xq8, Wq8, SA, RKS, packed, count, candCol);

    hipLaunchKernelGGL(rescore_kernel, dim3(NROWS / 4), dim3(256), 0, stream,
                       X, W, RK, RQ, count, candCol, outIdx, outSim, idxArr, MU, RS);
    hipLaunchKernelGGL(gemm2_kernel, dim3(D / 128, NROWS / 128), dim3(256), 0, stream,
                       X, W, idxArr, MU, RS, gamma, beta, OW, outO);
}